// Round 13
// baseline (81.048 us; speedup 1.0000x reference)
//
#include <hip/hip_runtime.h>
#include <hip/hip_bf16.h>

// ---------------------------------------------------------------------------
// MeshEstimator (SMPL-like) forward.  B=256, R=6890, 24 joints, 207 pose dims.
// R12 -> R13: k4_fused gets explicit software pipelines back (R6's proven
// fix): phase-2 prefetches next task's A-fragments into NAMED afc/afn arrays;
// phase-3 reinstates the cur/nxt rotation on At + vps loads. launch_bounds
// (512,4) so pipeline registers fit (~128 cap; VGPR was 40 = serialized).
// ---------------------------------------------------------------------------

#define NB 256
#define NR 6890
#define NJ 24
#define RD3 (NR*3)  // 20670
#define KPD 207
#define K2C 8       // k2 r-chunks
#define K2R 862     // rows per chunk
#define NT4 431     // vertex-tiles of 16 (431*16 = 6896 >= 6890)
#define BROW 232    // bsm row stride in bf16
#define VROW 133    // vps row stride in f32 (bank spread)

// ---- output offsets (floats) ----
#define OFF_BETAS 0
#define OFF_POSE  2560
#define OFF_RSH   20992
#define OFF_RA    21760
#define OFF_VERTS 23296
#define OFF_VRED  5314816
#define OFF_NEWJ  5322496
#define OFF_VOFF  5340928

// ---- workspace offsets (floats) ----
#define WS_RS    0         // Rs: 256*24*9 = 55296
#define WS_PF    55296     // pose_feat: 256*207 = 52992 -> ends 108288
#define WS_BETA  108288    // 2560
#define WS_RSH   110848    // 768
#define WS_GI    111616    // 256 ints
#define WS_ORD   111872    // 256 ints
#define WS_CNT   112128    // 2 ints (+2 pad)
#define WS_PFB   112904    // bf16 A-matrix: 2*256*224 ushort = 57344 floats
#define WS_AT    170248    // packed At per batch: hi[12][32]+lo[12][32] ushort

typedef short v8s __attribute__((ext_vector_type(8)));
typedef float v4f __attribute__((ext_vector_type(4)));

__constant__ int PAR_c[24] = {0,0,0,0,1,2,3,4,5,6,7,8,9,9,9,12,13,14,16,17,18,19,20,21};
__constant__ int VL_c[10]  = {1325,336,1032,4515,1374,4848,1739,5209,1960,5423};
__constant__ int SY_c[10]  = {3,15,4,5,7,8,18,19,20,21};
__constant__ int LVL_j[23]  = {1,2,3, 4,5,6, 7,8,9, 10,11,12,13,14, 15,16,17, 18,19, 20,21, 22,23};
__constant__ int LVL_off[9] = {0,3,6,9,14,17,19,21,23};

__constant__ float BLO[72] = {
  -0.5933865286111969f, -6.283185307179586f, -1.215762200416361f,
  -1.5793940868065197f, -0.5881754611f, -0.5323249722f,
  -1.5793940868065197f, -0.5689768556f, -0.6736965222f,
  -1.0471975511965976f, -0.08726646259971647f, -0.08726646259971647f,
  -0.02268926111f, -0.01f, -0.01f,
  -0.02268926111f, -0.01f, -0.01f,
  -1.0471975511965976f, -0.08726646259971647f, -0.08726646259971647f,
  -0.5235987755982988f, -0.5235987755982988f, -0.5235987755982988f,
  -0.5235987755982988f, -0.5235987755982988f, -0.5235987755982988f,
  -1.0471975511965976f, -0.08726646259971647f, -0.08726646259971647f,
  -0.01f, -0.01f, -0.01f, -0.01f, -0.01f, -0.01f,
  -1.0471975511965976f, -0.08726646259971647f, -0.08726646259971647f,
  (float)(-1.551596394/3.0), (float)(-2.455676183/3.0), (float)(-1.570795/3.0),
  (float)(-1.551596394/3.0), (float)(-0.7627082389/3.0), (float)(-2.188641033/3.0),
  -1.0471975511965976f, -0.08726646259971647f, -0.08726646259971647f,
  (float)(-1.551596394*2.0/3.0), (float)(-2.455676183*2.0/3.0), (float)(-1.570795*2.0/3.0),
  (float)(-1.551596394*2.0/3.0), (float)(-0.7627082389*2.0/3.0), (float)(-2.188641033*2.0/3.0),
  -0.01f, -2.570867817f, -0.01f, -0.01f, -0.04799651389f, -0.01f,
  -0.5235987755982988f, -0.5235987755982988f, -0.5235987755982988f,
  -0.5235987755982988f, -0.5235987755982988f, -0.5235987755982988f,
  -0.01f, -0.01f, -0.01f, -0.01f, -0.01f, -0.01f
};
__constant__ float BHI[72] = {
  0.5933865286111969f, 6.283185307179586f, 1.215762200416361f,
  0.3097956806f, 0.5689768556f, 0.6736965222f,
  0.3097956806f, 0.5881754611f, 0.5323249722f,
  1.0471975511965976f, 0.08726646259971647f, 0.08726646259971647f,
  2.441713561f, 0.01f, 0.01f,
  2.441713561f, 0.01f, 0.01f,
  1.0471975511965976f, 0.08726646259971647f, 0.08726646259971647f,
  0.5235987755982988f, 0.5235987755982988f, 0.5235987755982988f,
  0.5235987755982988f, 0.5235987755982988f, 0.5235987755982988f,
  1.0471975511965976f, 0.08726646259971647f, 0.08726646259971647f,
  0.01f, 0.01f, 0.01f, 0.01f, 0.01f, 0.01f,
  1.0471975511965976f, 0.08726646259971647f, 0.08726646259971647f,
  (float)(2.206094311/3.0), (float)(0.7627082389/3.0), (float)(2.188641033/3.0),
  (float)(2.206094311/3.0), (float)(2.455676183/3.0), (float)(1.570795/3.0),
  1.0471975511965976f, 0.08726646259971647f, 0.08726646259971647f,
  (float)(2.206094311*2.0/3.0), (float)(0.7627082389*2.0/3.0), (float)(2.188641033*2.0/3.0),
  (float)(2.206094311*2.0/3.0), (float)(2.455676183*2.0/3.0), (float)(1.570795*2.0/3.0),
  0.01f, 0.04799651389f, 0.01f, 0.01f, 2.570867817f, 0.01f,
  0.5235987755982988f, 0.5235987755982988f, 0.5235987755982988f,
  0.5235987755982988f, 0.5235987755982988f, 0.5235987755982988f,
  0.01f, 0.01f, 0.01f, 0.01f, 0.01f, 0.01f
};

__device__ __forceinline__ unsigned short f2bf(float f) {
  union { float f; unsigned u; } c; c.f = f;
  const unsigned u = c.u + 0x7FFFu + ((c.u >> 16) & 1u);   // RNE
  return (unsigned short)(u >> 16);
}
__device__ __forceinline__ float bf2f(unsigned short h) {
  union { unsigned u; float f; } c; c.u = (unsigned)h << 16; return c.f;
}

// ---------------------------------------------------------------------------
// kA: block-partitioned merge of k1 (per-batch pose, 256 blocks) and
// k2 (joint-regressor partials, 384 blocks). 256 threads.
// ---------------------------------------------------------------------------
__global__ void kA_front(const float* __restrict__ x, const float* __restrict__ gen,
                         const float* __restrict__ vtemp, const float* __restrict__ sdirs,
                         const float* __restrict__ jreg,
                         float* __restrict__ out, float* __restrict__ W)
{
  const int bid = blockIdx.x;
  const int tid = threadIdx.x;

  if (bid < NB) {
    const int b = bid;
    const float* xb = x + b * 88;
    if (tid < 24) {
      const int j = tid;
      float t[3];
      if (j == 0) {
        t[0] = atan2f(xb[16], xb[13]);
        t[1] = atan2f(xb[17], xb[14]);
        t[2] = atan2f(xb[18], xb[15]);
      } else {
        t[0] = xb[19 + (j - 1) * 3 + 0];
        t[1] = xb[19 + (j - 1) * 3 + 1];
        t[2] = xb[19 + (j - 1) * 3 + 2];
      }
#pragma unroll
      for (int c = 0; c < 3; c++) {
        const int pi = j * 3 + c;
        const float lo = 2.f * BLO[pi], hi = 2.f * BHI[pi];
        const float mean = 0.5f * (lo + hi);
        const float scale = 2.f / fabsf(lo - hi);
        const float v = tanhf((t[c] - mean) * scale) / scale + mean;
        t[c] = v;
        out[OFF_POSE + b * 72 + pi] = v;
      }
      const float a0 = t[0] + 1e-8f, a1 = t[1] + 1e-8f, a2 = t[2] + 1e-8f;
      const float ang = sqrtf(a0 * a0 + a1 * a1 + a2 * a2);
      const float half = 0.5f * ang;
      const float sh = sinf(half), ch = cosf(half);
      const float inv = sh / ang;
      float qw = ch, qx = t[0] * inv, qy = t[1] * inv, qz = t[2] * inv;
      const float nn = sqrtf(qw * qw + qx * qx + qy * qy + qz * qz);
      qw /= nn; qx /= nn; qy /= nn; qz /= nn;
      float R[9];
      R[0] = 1.f - 2.f * (qy * qy + qz * qz); R[1] = 2.f * (qx * qy - qw * qz); R[2] = 2.f * (qx * qz + qw * qy);
      R[3] = 2.f * (qx * qy + qw * qz); R[4] = 1.f - 2.f * (qx * qx + qz * qz); R[5] = 2.f * (qy * qz - qw * qx);
      R[6] = 2.f * (qx * qz - qw * qy); R[7] = 2.f * (qy * qz + qw * qx); R[8] = 1.f - 2.f * (qx * qx + qy * qy);
      float* rsw = W + WS_RS + (size_t)(b * 24 + j) * 9;
#pragma unroll
      for (int e = 0; e < 9; e++) rsw[e] = R[e];
      if (j >= 1) {
        float* pfw = W + WS_PF + (size_t)b * 207 + (j - 1) * 9;
#pragma unroll
        for (int e = 0; e < 9; e++)
          pfw[e] = R[e] - ((e == 0 || e == 4 || e == 8) ? 1.f : 0.f);
      }
    } else if (tid < 34) {
      const int k = tid - 24;
      const float v = tanhf(xb[k] / 3.0f) * 3.0f;
      out[OFF_BETAS + b * 10 + k] = v;
      W[WS_BETA + b * 10 + k] = v;
    } else if (tid == 34) {
      const float r0 = xb[10] + (0.6f - 0.286f);
      const float r1 = xb[11] + (1.2f - 0.286f);
      const float r2 = xb[12] + 0.1f;
      out[OFF_RSH + b * 3 + 0] = r0; out[OFF_RSH + b * 3 + 1] = r1; out[OFF_RSH + b * 3 + 2] = r2;
      W[WS_RSH + b * 3 + 0] = r0; W[WS_RSH + b * 3 + 1] = r1; W[WS_RSH + b * 3 + 2] = r2;
#pragma unroll
      for (int k2 = 0; k2 < 6; k2++) out[OFF_RA + b * 6 + k2] = xb[13 + k2];
    } else if (tid == 35) {
      ((int*)(W + WS_GI))[b] = (gen[b * 2 + 1] > gen[b * 2 + 0]) ? 1 : 0;
    }
    return;
  }

  // ---------------- k2 part ----------------
  const int kb = bid - NB;
  const int c = kb % K2C, j = (kb / K2C) % 24, g = kb / (K2C * 24);
  const int r0 = c * K2R;
  int r1 = r0 + K2R; if (r1 > NR) r1 = NR;
  const float* vtg = vtemp + (size_t)g * NR * 3;
  const float* sdg = sdirs + (size_t)g * 10 * NR * 3;
  const float* jrg = jreg + (size_t)g * NR * 24;
  float acc[33];
#pragma unroll
  for (int e = 0; e < 33; e++) acc[e] = 0.f;
  for (int r = r0 + tid; r < r1; r += 256) {
    const float w = jrg[r * 24 + j];
    acc[0] += vtg[r * 3 + 0] * w;
    acc[1] += vtg[r * 3 + 1] * w;
    acc[2] += vtg[r * 3 + 2] * w;
#pragma unroll
    for (int k = 0; k < 10; k++) {
      const float* s = sdg + ((size_t)k * NR + r) * 3;
      acc[3 + k * 3 + 0] += s[0] * w;
      acc[3 + k * 3 + 1] += s[1] * w;
      acc[3 + k * 3 + 2] += s[2] * w;
    }
  }
  __shared__ float red[4][33];
  const int lane = tid & 63, wv = tid >> 6;
#pragma unroll
  for (int e = 0; e < 33; e++) {
    float v = acc[e];
    v += __shfl_down(v, 32); v += __shfl_down(v, 16); v += __shfl_down(v, 8);
    v += __shfl_down(v, 4);  v += __shfl_down(v, 2);  v += __shfl_down(v, 1);
    if (lane == 0) red[wv][e] = v;
  }
  __syncthreads();
  if (tid < 33) {
    const int e = tid;
    out[OFF_VERTS + (size_t)(((g * 24 + j) * K2C + c) * 33 + e)] =
        red[0][e] + red[1][e] + red[2][e] + red[3][e];
  }
}

// ---------------------------------------------------------------------------
// kB: merge of (in-block gender compaction + PFB pack, 512 blocks) and
// k3 kinematic chain (256 blocks). 256 threads.
// ---------------------------------------------------------------------------
__global__ void kB_mid(float* __restrict__ out, float* __restrict__ W)
{
  const int bid = blockIdx.x;
  const int tid = threadIdx.x;

  if (bid < 512) {
    __shared__ int s_ord[NB];
    __shared__ int s_c0[4];
    const int gib = ((const int*)(W + WS_GI))[tid];
    const int lane = tid & 63, wvi = tid >> 6;
    const unsigned long long b0 = __ballot(gib == 0);
    if (lane == 0) s_c0[wvi] = __popcll(b0);
    __syncthreads();
    const int t0 = s_c0[0] + s_c0[1] + s_c0[2] + s_c0[3];
    int off0 = 0, off1 = t0;
    for (int w = 0; w < wvi; w++) { off0 += s_c0[w]; off1 += 64 - s_c0[w]; }
    const unsigned long long ltm = (1ull << lane) - 1ull;
    const int rr0 = __popcll(b0 & ltm);
    const int rr1 = lane - rr0;
    if (gib == 0) s_ord[off0 + rr0] = tid;
    else          s_ord[off1 + rr1] = tid;
    __syncthreads();

    if (bid == 0) {
      ((int*)(W + WS_ORD))[tid] = s_ord[tid];
      if (tid == 0) { ((int*)(W + WS_CNT))[0] = t0; ((int*)(W + WS_CNT))[1] = NB - t0; }
    }

    const int g = bid >> 8, m = bid & 255;
    const int n_g = g ? (NB - t0) : t0;
    const int g0off = g ? t0 : 0;
    if (tid < 224) {
      float v = 0.f;
      if (m < n_g) {
        const int b = s_ord[g0off + m];
        if (tid < KPD)        v = W[WS_PF + (size_t)b * KPD + tid];
        else if (tid < 217)   v = W[WS_BETA + b * 10 + (tid - KPD)];
        else if (tid == 217)  v = 1.f;
      }
      ((unsigned short*)(W + WS_PFB))[((size_t)g * 256 + m) * 224 + tid] = f2bf(v);
    }
    return;
  }

  // -------- k3 part: b = bid - 512 --------
  const int b = bid - 512;
  __shared__ float J[72];
  __shared__ float G[24][12];
  __shared__ float sA[24][12];
  __shared__ float j0s[3];
  const int gi = ((const int*)(W + WS_GI))[b];
  float bb[10];
#pragma unroll
  for (int k = 0; k < 10; k++) bb[k] = W[WS_BETA + b * 10 + k];

  if (tid < 72) {
    const int j = tid / 3, d = tid % 3;
    float v = 0.f;
#pragma unroll
    for (int c = 0; c < K2C; c++) {
      const float* P = out + OFF_VERTS + (size_t)(((gi * 24 + j) * K2C + c) * 33);
      float s = P[d];
#pragma unroll
      for (int k = 0; k < 10; k++) s += bb[k] * P[3 + k * 3 + d];
      v += s;
    }
    J[tid] = v;
  }
  __syncthreads();
  const float* Rs = W + WS_RS + (size_t)b * 216;
  if (tid < 12) {
    const int row = tid / 4, col = tid % 4;
    G[0][tid] = (col < 3) ? Rs[row * 3 + col] : J[row];
  }
  __syncthreads();
#pragma unroll
  for (int L = 0; L < 8; L++) {
    const int base = LVL_off[L];
    const int cntL = LVL_off[L + 1] - base;
    const int slot = tid / 12, e = tid - slot * 12;
    if (slot < cntL) {
      const int i = LVL_j[base + slot];
      const int p = PAR_c[i];
      const int row = e / 4, col = e - row * 4;
      const float* Ri = Rs + i * 9;
      const float g0 = G[p][row * 4 + 0], g1 = G[p][row * 4 + 1], g2 = G[p][row * 4 + 2];
      float v;
      if (col < 3) {
        v = g0 * Ri[col] + g1 * Ri[3 + col] + g2 * Ri[6 + col];
      } else {
        const float t0 = J[i * 3 + 0] - J[p * 3 + 0];
        const float t1 = J[i * 3 + 1] - J[p * 3 + 1];
        const float t2 = J[i * 3 + 2] - J[p * 3 + 2];
        v = g0 * t0 + g1 * t1 + g2 * t2 + G[p][row * 4 + 3];
      }
      G[i][e] = v;
    }
    __syncthreads();
  }
  if (tid < 3)
    j0s[tid] = W[WS_RSH + b * 3 + tid] - J[tid];
  __syncthreads();
  if (tid < 72) {
    const int j = tid / 3, d = tid % 3;
    out[OFF_NEWJ + (size_t)b * 72 + tid] = G[j][d * 4 + 3] + j0s[d];
  }
  for (int e = tid; e < 288; e += 256) {
    const int j = e / 12, rc = e - j * 12, row = rc / 4, col = rc - row * 4;
    float v = G[j][rc];
    if (col == 3)
      v -= G[j][row * 4 + 0] * J[j * 3 + 0] + G[j][row * 4 + 1] * J[j * 3 + 1] + G[j][row * 4 + 2] * J[j * 3 + 2];
    sA[j][rc] = v;
  }
  __syncthreads();
  unsigned short* at = (unsigned short*)(W + WS_AT) + (size_t)b * 768;
  for (int e = tid; e < 384; e += 256) {
    const int c = e >> 5, j = e & 31;
    float a = 0.f;
    if (j < 24) a = sA[j][c];
    else if (j == 24) a = ((c & 3) == 3) ? j0s[c >> 2] : 0.f;
    const unsigned short h = f2bf(a);
    const unsigned short l = f2bf(a - bf2f(h));
    at[c * 32 + j] = h;
    at[384 + c * 32 + j] = l;
  }
}

// ---------------------------------------------------------------------------
// K4 fused (512 threads / 8 waves), software-pipelined phases 2 and 3.
// Grid: x = vertex tile (16 verts = 48 n-rows), y = (gender, batch-half).
// ---------------------------------------------------------------------------
__launch_bounds__(512, 4)
__global__ void k4_fused(const float* __restrict__ pd, const float* __restrict__ vtemp,
                         const float* __restrict__ sdirs, const float* __restrict__ wts,
                         float* __restrict__ out, const float* __restrict__ W)
{
  __shared__ __align__(16) unsigned short bsm[48][BROW];
  __shared__ float vps[48][VROW];
  __shared__ int s_ord[NB];

  const int tid = threadIdx.x;
  const int wave = tid >> 6, lane = tid & 63;
  const int g = blockIdx.y >> 1, h = blockIdx.y & 1;
  const int nfrac = lane & 15;
  const int kq = (lane >> 4) * 8;
  const int tile = blockIdx.x;
  const int n0 = tile * 48;
  const int rbase = tile * 16;

  const int* cnt = (const int*)(W + WS_CNT);
  const int* ord = (const int*)(W + WS_ORD);
  const int n_g = cnt[g];
  const int g0off = g ? cnt[0] : 0;
  int nh = n_g - h * 128; if (nh > 128) nh = 128;
  if (nh <= 0) return;   // uniform, before any barrier

  if (tid < NB) s_ord[tid] = ord[tid];

  // ---- Phase 1: stage B tile (512 threads: 5 rounds of 16B) ----
  const int nrows = (RD3 - n0 < 48) ? (RD3 - n0) : 48;
  const int nflat = nrows * KPD;                     // <= 9936
  const float* src = pd + ((size_t)g * RD3 + n0) * KPD;
#pragma unroll
  for (int i = 0; i < 5; i++) {
    const int e4 = (i * 512 + tid) * 4;
    if (e4 + 3 < nflat) {
      float v[4];
      __builtin_memcpy(v, src + e4, 16);
#pragma unroll
      for (int t = 0; t < 4; t++) {
        const int fl = e4 + t;
        bsm[fl / KPD][fl % KPD] = f2bf(v[t]);
      }
    } else if (e4 < nflat) {
      for (int t = 0; t < 4 && e4 + t < nflat; t++)
        bsm[(e4 + t) / KPD][(e4 + t) % KPD] = f2bf(src[e4 + t]);
    }
  }
  if (tid < 48) {
    const int nr = (n0 + tid < RD3) ? (n0 + tid) : (RD3 - 1);
    const int rr = nr / 3, dd = nr - rr * 3;
#pragma unroll
    for (int kk = 0; kk < 10; kk++)
      bsm[tid][KPD + kk] = f2bf(sdirs[((size_t)(g * 10 + kk) * NR + rr) * 3 + dd]);
    bsm[tid][217] = f2bf(vtemp[((size_t)g * NR + rr) * 3 + dd]);
#pragma unroll
    for (int kk = 218; kk < 224; kk++) bsm[tid][kk] = 0;
  }
  __syncthreads();

  // ---- Phase 2: GEMM tasks -> vps, 2-stage pipeline on A-fragments ----
  const unsigned short* pfb = (const unsigned short*)(W + WS_PFB) + (size_t)g * 256 * 224;
  const int mtmax_h = (nh + 15) >> 4;
  const int ntasks = 3 * mtmax_h;

  v8s afc[7];
  if (wave < ntasks) {
    const int mt0 = wave / 3;
    const unsigned short* ap0 = pfb + (size_t)(h * 128 + mt0 * 16 + nfrac) * 224 + kq;
#pragma unroll
    for (int c = 0; c < 7; c++) afc[c] = *(const v8s*)(ap0 + c * 32);
  }
  for (int t = wave; t < ntasks; t += 8) {
    // prefetch next task's A-fragments (L2-latency hidden under MFMAs)
    const int tn = (t + 8 < ntasks) ? (t + 8) : t;
    const int mtn = tn / 3;
    const unsigned short* apn = pfb + (size_t)(h * 128 + mtn * 16 + nfrac) * 224 + kq;
    v8s afn[7];
#pragma unroll
    for (int c = 0; c < 7; c++) afn[c] = *(const v8s*)(apn + c * 32);

    const int s = t % 3, mt = t / 3;
    const unsigned short* bp = &bsm[s * 16 + nfrac][0];
    v8s bfr[7];
#pragma unroll
    for (int c = 0; c < 7; c++) bfr[c] = *(const v8s*)(bp + c * 32 + kq);

    v4f acc0 = {0.f, 0.f, 0.f, 0.f};
    v4f acc1 = {0.f, 0.f, 0.f, 0.f};
    acc0 = __builtin_amdgcn_mfma_f32_16x16x32_bf16(afc[0], bfr[0], acc0, 0, 0, 0);
    acc1 = __builtin_amdgcn_mfma_f32_16x16x32_bf16(afc[1], bfr[1], acc1, 0, 0, 0);
    acc0 = __builtin_amdgcn_mfma_f32_16x16x32_bf16(afc[2], bfr[2], acc0, 0, 0, 0);
    acc1 = __builtin_amdgcn_mfma_f32_16x16x32_bf16(afc[3], bfr[3], acc1, 0, 0, 0);
    acc0 = __builtin_amdgcn_mfma_f32_16x16x32_bf16(afc[4], bfr[4], acc0, 0, 0, 0);
    acc1 = __builtin_amdgcn_mfma_f32_16x16x32_bf16(afc[5], bfr[5], acc1, 0, 0, 0);
    acc0 = __builtin_amdgcn_mfma_f32_16x16x32_bf16(afc[6], bfr[6], acc0, 0, 0, 0);

    const int ln = s * 16 + nfrac;
    const int lm0 = mt * 16 + (lane >> 4) * 4;
#pragma unroll
    for (int j = 0; j < 4; j++)
      vps[ln][lm0 + j] = acc0[j] + acc1[j];

#pragma unroll
    for (int c = 0; c < 7; c++) afc[c] = afn[c];
  }
  __syncthreads();

  // ---- Phase 3: skinning, cur/nxt rotation on At + vps loads ----
  const int f = nfrac, q = lane >> 4;
  const int r = rbase + f;
  const int rc = (r < NR) ? r : (NR - 1);

  int vli = -1;
#pragma unroll
  for (int i = 0; i < 10; i++) if (r == VL_c[i]) vli = i;
  const int syj = (vli >= 0) ? SY_c[vli] : 0;

  v8s wh, wl;
  {
    union { v8s v; unsigned short s[8]; } H, L;
    if (q < 3) {
      float fw[8];
      __builtin_memcpy(fw, wts + ((size_t)g * NR + rc) * 24 + q * 8, 32);
#pragma unroll
      for (int t = 0; t < 8; t++) { H.s[t] = f2bf(fw[t]); L.s[t] = f2bf(fw[t] - bf2f(H.s[t])); }
    } else {
#pragma unroll
      for (int t = 0; t < 8; t++) { H.s[t] = (t == 0) ? 0x3F80 : 0; L.s[t] = 0; }
    }
    wh = H.v; wl = L.v;
  }

  const unsigned short* at = (const unsigned short*)(W + WS_AT);
  const int fragoff = f * 32 + q * 8;
  const int mbase = g0off + h * 128;

  if (wave < nh) {
    int b_cur = s_ord[mbase + wave];
    v8s ah_cur = *(const v8s*)(at + (size_t)b_cur * 768 + fragoff);
    v8s al_cur = *(const v8s*)(at + (size_t)b_cur * 768 + 384 + fragoff);
    float vx_cur = vps[f * 3 + 0][wave];
    float vy_cur = vps[f * 3 + 1][wave];
    float vz_cur = vps[f * 3 + 2][wave];

    for (int lm = wave; lm < nh; lm += 8) {
      const int lm2 = (lm + 8 < nh) ? (lm + 8) : lm;
      const int b_nxt = s_ord[mbase + lm2];
      const v8s ah_nxt = *(const v8s*)(at + (size_t)b_nxt * 768 + fragoff);
      const v8s al_nxt = *(const v8s*)(at + (size_t)b_nxt * 768 + 384 + fragoff);
      const float vx_nxt = vps[f * 3 + 0][lm2];
      const float vy_nxt = vps[f * 3 + 1][lm2];
      const float vz_nxt = vps[f * 3 + 2][lm2];

      v4f acc = {0.f, 0.f, 0.f, 0.f};
      acc = __builtin_amdgcn_mfma_f32_16x16x32_bf16(ah_cur, wh, acc, 0, 0, 0);
      acc = __builtin_amdgcn_mfma_f32_16x16x32_bf16(ah_cur, wl, acc, 0, 0, 0);
      acc = __builtin_amdgcn_mfma_f32_16x16x32_bf16(al_cur, wh, acc, 0, 0, 0);
      const float o = acc[0] * vx_cur + acc[1] * vy_cur + acc[2] * vz_cur + acc[3];
      if (q < 3 && r < NR) {
        out[OFF_VERTS + ((size_t)b_cur * NR + r) * 3 + q] = o;
        if (vli >= 0) {
          out[OFF_VRED + ((size_t)b_cur * 10 + vli) * 3 + q] = o;
          out[OFF_VOFF + ((size_t)b_cur * 10 + vli) * 3 + q] =
              o - out[OFF_NEWJ + (size_t)b_cur * 72 + syj * 3 + q];
        }
      }

      b_cur = b_nxt; ah_cur = ah_nxt; al_cur = al_nxt;
      vx_cur = vx_nxt; vy_cur = vy_nxt; vz_cur = vz_nxt;
    }
  }
}

// ---------------------------------------------------------------------------
extern "C" void kernel_launch(void* const* d_in, const int* in_sizes, int n_in,
                              void* d_out, int out_size, void* d_ws, size_t ws_size,
                              hipStream_t stream)
{
  const float* x   = (const float*)d_in[0];
  const float* gen = (const float*)d_in[1];
  const float* vt  = (const float*)d_in[2];
  const float* sd  = (const float*)d_in[3];
  const float* jr  = (const float*)d_in[4];
  const float* pd  = (const float*)d_in[5];
  const float* wt  = (const float*)d_in[6];
  float* out = (float*)d_out;
  float* W   = (float*)d_ws;

  kA_front<<<NB + 2 * 24 * K2C, 256, 0, stream>>>(x, gen, vt, sd, jr, out, W);
  kB_mid<<<512 + NB, 256, 0, stream>>>(out, W);
  k4_fused<<<dim3(NT4, 4), 512, 0, stream>>>(pd, vt, sd, wt, out, W);
}

// Round 14
// 77.933 us; speedup vs baseline: 1.0400x; 1.0400x over previous
//
#include <hip/hip_runtime.h>
#include <hip/hip_bf16.h>

// ---------------------------------------------------------------------------
// MeshEstimator (SMPL-like) forward.  B=256, R=6890, 24 joints, 207 pose dims.
// R13 -> R14: k4_fused occupancy + MLP rework (compiler-proof levers only):
//  - grid y=2 (gender): no dead blocks (was: h-halves, 50% exited instantly)
//  - vps stored bf16 -> LDS 48.6KB -> 3 blocks/CU (24 waves) @ (512,6)
//  - phase1: all 20 staging loads issued before any LDS write (R10 idiom)
//  - phase3: two batches per iteration (independent named operand sets)
//  - ext-col staging spread over 480 threads (was 48 thr x 11 serial gathers)
// ---------------------------------------------------------------------------

#define NB 256
#define NR 6890
#define NJ 24
#define RD3 (NR*3)  // 20670
#define KPD 207
#define K2C 8       // k2 r-chunks
#define K2R 862     // rows per chunk
#define NT4 431     // vertex-tiles of 16 (431*16 = 6896 >= 6890)
#define BROW 232    // bsm row stride in bf16 (464B = 29*16)
#define VROWB 264   // vps row stride in bf16 (528B = 33*16)

// ---- output offsets (floats) ----
#define OFF_BETAS 0
#define OFF_POSE  2560
#define OFF_RSH   20992
#define OFF_RA    21760
#define OFF_VERTS 23296
#define OFF_VRED  5314816
#define OFF_NEWJ  5322496
#define OFF_VOFF  5340928

// ---- workspace offsets (floats) ----
#define WS_RS    0         // Rs: 256*24*9 = 55296
#define WS_PF    55296     // pose_feat: 256*207 = 52992 -> ends 108288
#define WS_BETA  108288    // 2560
#define WS_RSH   110848    // 768
#define WS_GI    111616    // 256 ints
#define WS_ORD   111872    // 256 ints
#define WS_CNT   112128    // 2 ints (+2 pad)
#define WS_PFB   112904    // bf16 A-matrix: 2*256*224 ushort = 57344 floats
#define WS_AT    170248    // packed At per batch: hi[12][32]+lo[12][32] ushort

typedef short v8s __attribute__((ext_vector_type(8)));
typedef float v4f __attribute__((ext_vector_type(4)));

__constant__ int PAR_c[24] = {0,0,0,0,1,2,3,4,5,6,7,8,9,9,9,12,13,14,16,17,18,19,20,21};
__constant__ int VL_c[10]  = {1325,336,1032,4515,1374,4848,1739,5209,1960,5423};
__constant__ int SY_c[10]  = {3,15,4,5,7,8,18,19,20,21};
__constant__ int LVL_j[23]  = {1,2,3, 4,5,6, 7,8,9, 10,11,12,13,14, 15,16,17, 18,19, 20,21, 22,23};
__constant__ int LVL_off[9] = {0,3,6,9,14,17,19,21,23};

__constant__ float BLO[72] = {
  -0.5933865286111969f, -6.283185307179586f, -1.215762200416361f,
  -1.5793940868065197f, -0.5881754611f, -0.5323249722f,
  -1.5793940868065197f, -0.5689768556f, -0.6736965222f,
  -1.0471975511965976f, -0.08726646259971647f, -0.08726646259971647f,
  -0.02268926111f, -0.01f, -0.01f,
  -0.02268926111f, -0.01f, -0.01f,
  -1.0471975511965976f, -0.08726646259971647f, -0.08726646259971647f,
  -0.5235987755982988f, -0.5235987755982988f, -0.5235987755982988f,
  -0.5235987755982988f, -0.5235987755982988f, -0.5235987755982988f,
  -1.0471975511965976f, -0.08726646259971647f, -0.08726646259971647f,
  -0.01f, -0.01f, -0.01f, -0.01f, -0.01f, -0.01f,
  -1.0471975511965976f, -0.08726646259971647f, -0.08726646259971647f,
  (float)(-1.551596394/3.0), (float)(-2.455676183/3.0), (float)(-1.570795/3.0),
  (float)(-1.551596394/3.0), (float)(-0.7627082389/3.0), (float)(-2.188641033/3.0),
  -1.0471975511965976f, -0.08726646259971647f, -0.08726646259971647f,
  (float)(-1.551596394*2.0/3.0), (float)(-2.455676183*2.0/3.0), (float)(-1.570795*2.0/3.0),
  (float)(-1.551596394*2.0/3.0), (float)(-0.7627082389*2.0/3.0), (float)(-2.188641033*2.0/3.0),
  -0.01f, -2.570867817f, -0.01f, -0.01f, -0.04799651389f, -0.01f,
  -0.5235987755982988f, -0.5235987755982988f, -0.5235987755982988f,
  -0.5235987755982988f, -0.5235987755982988f, -0.5235987755982988f,
  -0.01f, -0.01f, -0.01f, -0.01f, -0.01f, -0.01f
};
__constant__ float BHI[72] = {
  0.5933865286111969f, 6.283185307179586f, 1.215762200416361f,
  0.3097956806f, 0.5689768556f, 0.6736965222f,
  0.3097956806f, 0.5881754611f, 0.5323249722f,
  1.0471975511965976f, 0.08726646259971647f, 0.08726646259971647f,
  2.441713561f, 0.01f, 0.01f,
  2.441713561f, 0.01f, 0.01f,
  1.0471975511965976f, 0.08726646259971647f, 0.08726646259971647f,
  0.5235987755982988f, 0.5235987755982988f, 0.5235987755982988f,
  0.5235987755982988f, 0.5235987755982988f, 0.5235987755982988f,
  1.0471975511965976f, 0.08726646259971647f, 0.08726646259971647f,
  0.01f, 0.01f, 0.01f, 0.01f, 0.01f, 0.01f,
  1.0471975511965976f, 0.08726646259971647f, 0.08726646259971647f,
  (float)(2.206094311/3.0), (float)(0.7627082389/3.0), (float)(2.188641033/3.0),
  (float)(2.206094311/3.0), (float)(2.455676183/3.0), (float)(1.570795/3.0),
  1.0471975511965976f, 0.08726646259971647f, 0.08726646259971647f,
  (float)(2.206094311*2.0/3.0), (float)(0.7627082389*2.0/3.0), (float)(2.188641033*2.0/3.0),
  (float)(2.206094311*2.0/3.0), (float)(2.455676183*2.0/3.0), (float)(1.570795*2.0/3.0),
  0.01f, 0.04799651389f, 0.01f, 0.01f, 2.570867817f, 0.01f,
  0.5235987755982988f, 0.5235987755982988f, 0.5235987755982988f,
  0.5235987755982988f, 0.5235987755982988f, 0.5235987755982988f,
  0.01f, 0.01f, 0.01f, 0.01f, 0.01f, 0.01f
};

__device__ __forceinline__ unsigned short f2bf(float f) {
  union { float f; unsigned u; } c; c.f = f;
  const unsigned u = c.u + 0x7FFFu + ((c.u >> 16) & 1u);   // RNE
  return (unsigned short)(u >> 16);
}
__device__ __forceinline__ float bf2f(unsigned short h) {
  union { unsigned u; float f; } c; c.u = (unsigned)h << 16; return c.f;
}

// ---------------------------------------------------------------------------
// kA: block-partitioned merge of k1 (per-batch pose, 256 blocks) and
// k2 (joint-regressor partials, 384 blocks). 256 threads.
// ---------------------------------------------------------------------------
__global__ void kA_front(const float* __restrict__ x, const float* __restrict__ gen,
                         const float* __restrict__ vtemp, const float* __restrict__ sdirs,
                         const float* __restrict__ jreg,
                         float* __restrict__ out, float* __restrict__ W)
{
  const int bid = blockIdx.x;
  const int tid = threadIdx.x;

  if (bid < NB) {
    const int b = bid;
    const float* xb = x + b * 88;
    if (tid < 24) {
      const int j = tid;
      float t[3];
      if (j == 0) {
        t[0] = atan2f(xb[16], xb[13]);
        t[1] = atan2f(xb[17], xb[14]);
        t[2] = atan2f(xb[18], xb[15]);
      } else {
        t[0] = xb[19 + (j - 1) * 3 + 0];
        t[1] = xb[19 + (j - 1) * 3 + 1];
        t[2] = xb[19 + (j - 1) * 3 + 2];
      }
#pragma unroll
      for (int c = 0; c < 3; c++) {
        const int pi = j * 3 + c;
        const float lo = 2.f * BLO[pi], hi = 2.f * BHI[pi];
        const float mean = 0.5f * (lo + hi);
        const float scale = 2.f / fabsf(lo - hi);
        const float v = tanhf((t[c] - mean) * scale) / scale + mean;
        t[c] = v;
        out[OFF_POSE + b * 72 + pi] = v;
      }
      const float a0 = t[0] + 1e-8f, a1 = t[1] + 1e-8f, a2 = t[2] + 1e-8f;
      const float ang = sqrtf(a0 * a0 + a1 * a1 + a2 * a2);
      const float half = 0.5f * ang;
      const float sh = sinf(half), ch = cosf(half);
      const float inv = sh / ang;
      float qw = ch, qx = t[0] * inv, qy = t[1] * inv, qz = t[2] * inv;
      const float nn = sqrtf(qw * qw + qx * qx + qy * qy + qz * qz);
      qw /= nn; qx /= nn; qy /= nn; qz /= nn;
      float R[9];
      R[0] = 1.f - 2.f * (qy * qy + qz * qz); R[1] = 2.f * (qx * qy - qw * qz); R[2] = 2.f * (qx * qz + qw * qy);
      R[3] = 2.f * (qx * qy + qw * qz); R[4] = 1.f - 2.f * (qx * qx + qz * qz); R[5] = 2.f * (qy * qz - qw * qx);
      R[6] = 2.f * (qx * qz - qw * qy); R[7] = 2.f * (qy * qz + qw * qx); R[8] = 1.f - 2.f * (qx * qx + qy * qy);
      float* rsw = W + WS_RS + (size_t)(b * 24 + j) * 9;
#pragma unroll
      for (int e = 0; e < 9; e++) rsw[e] = R[e];
      if (j >= 1) {
        float* pfw = W + WS_PF + (size_t)b * 207 + (j - 1) * 9;
#pragma unroll
        for (int e = 0; e < 9; e++)
          pfw[e] = R[e] - ((e == 0 || e == 4 || e == 8) ? 1.f : 0.f);
      }
    } else if (tid < 34) {
      const int k = tid - 24;
      const float v = tanhf(xb[k] / 3.0f) * 3.0f;
      out[OFF_BETAS + b * 10 + k] = v;
      W[WS_BETA + b * 10 + k] = v;
    } else if (tid == 34) {
      const float r0 = xb[10] + (0.6f - 0.286f);
      const float r1 = xb[11] + (1.2f - 0.286f);
      const float r2 = xb[12] + 0.1f;
      out[OFF_RSH + b * 3 + 0] = r0; out[OFF_RSH + b * 3 + 1] = r1; out[OFF_RSH + b * 3 + 2] = r2;
      W[WS_RSH + b * 3 + 0] = r0; W[WS_RSH + b * 3 + 1] = r1; W[WS_RSH + b * 3 + 2] = r2;
#pragma unroll
      for (int k2 = 0; k2 < 6; k2++) out[OFF_RA + b * 6 + k2] = xb[13 + k2];
    } else if (tid == 35) {
      ((int*)(W + WS_GI))[b] = (gen[b * 2 + 1] > gen[b * 2 + 0]) ? 1 : 0;
    }
    return;
  }

  // ---------------- k2 part ----------------
  const int kb = bid - NB;
  const int c = kb % K2C, j = (kb / K2C) % 24, g = kb / (K2C * 24);
  const int r0 = c * K2R;
  int r1 = r0 + K2R; if (r1 > NR) r1 = NR;
  const float* vtg = vtemp + (size_t)g * NR * 3;
  const float* sdg = sdirs + (size_t)g * 10 * NR * 3;
  const float* jrg = jreg + (size_t)g * NR * 24;
  float acc[33];
#pragma unroll
  for (int e = 0; e < 33; e++) acc[e] = 0.f;
  for (int r = r0 + tid; r < r1; r += 256) {
    const float w = jrg[r * 24 + j];
    acc[0] += vtg[r * 3 + 0] * w;
    acc[1] += vtg[r * 3 + 1] * w;
    acc[2] += vtg[r * 3 + 2] * w;
#pragma unroll
    for (int k = 0; k < 10; k++) {
      const float* s = sdg + ((size_t)k * NR + r) * 3;
      acc[3 + k * 3 + 0] += s[0] * w;
      acc[3 + k * 3 + 1] += s[1] * w;
      acc[3 + k * 3 + 2] += s[2] * w;
    }
  }
  __shared__ float red[4][33];
  const int lane = tid & 63, wv = tid >> 6;
#pragma unroll
  for (int e = 0; e < 33; e++) {
    float v = acc[e];
    v += __shfl_down(v, 32); v += __shfl_down(v, 16); v += __shfl_down(v, 8);
    v += __shfl_down(v, 4);  v += __shfl_down(v, 2);  v += __shfl_down(v, 1);
    if (lane == 0) red[wv][e] = v;
  }
  __syncthreads();
  if (tid < 33) {
    const int e = tid;
    out[OFF_VERTS + (size_t)(((g * 24 + j) * K2C + c) * 33 + e)] =
        red[0][e] + red[1][e] + red[2][e] + red[3][e];
  }
}

// ---------------------------------------------------------------------------
// kB: merge of (in-block gender compaction + PFB pack, 512 blocks) and
// k3 kinematic chain (256 blocks). 256 threads.
// ---------------------------------------------------------------------------
__global__ void kB_mid(float* __restrict__ out, float* __restrict__ W)
{
  const int bid = blockIdx.x;
  const int tid = threadIdx.x;

  if (bid < 512) {
    __shared__ int s_ord[NB];
    __shared__ int s_c0[4];
    const int gib = ((const int*)(W + WS_GI))[tid];
    const int lane = tid & 63, wvi = tid >> 6;
    const unsigned long long b0 = __ballot(gib == 0);
    if (lane == 0) s_c0[wvi] = __popcll(b0);
    __syncthreads();
    const int t0 = s_c0[0] + s_c0[1] + s_c0[2] + s_c0[3];
    int off0 = 0, off1 = t0;
    for (int w = 0; w < wvi; w++) { off0 += s_c0[w]; off1 += 64 - s_c0[w]; }
    const unsigned long long ltm = (1ull << lane) - 1ull;
    const int rr0 = __popcll(b0 & ltm);
    const int rr1 = lane - rr0;
    if (gib == 0) s_ord[off0 + rr0] = tid;
    else          s_ord[off1 + rr1] = tid;
    __syncthreads();

    if (bid == 0) {
      ((int*)(W + WS_ORD))[tid] = s_ord[tid];
      if (tid == 0) { ((int*)(W + WS_CNT))[0] = t0; ((int*)(W + WS_CNT))[1] = NB - t0; }
    }

    const int g = bid >> 8, m = bid & 255;
    const int n_g = g ? (NB - t0) : t0;
    const int g0off = g ? t0 : 0;
    if (tid < 224) {
      float v = 0.f;
      if (m < n_g) {
        const int b = s_ord[g0off + m];
        if (tid < KPD)        v = W[WS_PF + (size_t)b * KPD + tid];
        else if (tid < 217)   v = W[WS_BETA + b * 10 + (tid - KPD)];
        else if (tid == 217)  v = 1.f;
      }
      ((unsigned short*)(W + WS_PFB))[((size_t)g * 256 + m) * 224 + tid] = f2bf(v);
    }
    return;
  }

  // -------- k3 part: b = bid - 512 --------
  const int b = bid - 512;
  __shared__ float J[72];
  __shared__ float G[24][12];
  __shared__ float sA[24][12];
  __shared__ float j0s[3];
  const int gi = ((const int*)(W + WS_GI))[b];
  float bb[10];
#pragma unroll
  for (int k = 0; k < 10; k++) bb[k] = W[WS_BETA + b * 10 + k];

  if (tid < 72) {
    const int j = tid / 3, d = tid % 3;
    float v = 0.f;
#pragma unroll
    for (int c = 0; c < K2C; c++) {
      const float* P = out + OFF_VERTS + (size_t)(((gi * 24 + j) * K2C + c) * 33);
      float s = P[d];
#pragma unroll
      for (int k = 0; k < 10; k++) s += bb[k] * P[3 + k * 3 + d];
      v += s;
    }
    J[tid] = v;
  }
  __syncthreads();
  const float* Rs = W + WS_RS + (size_t)b * 216;
  if (tid < 12) {
    const int row = tid / 4, col = tid % 4;
    G[0][tid] = (col < 3) ? Rs[row * 3 + col] : J[row];
  }
  __syncthreads();
#pragma unroll
  for (int L = 0; L < 8; L++) {
    const int base = LVL_off[L];
    const int cntL = LVL_off[L + 1] - base;
    const int slot = tid / 12, e = tid - slot * 12;
    if (slot < cntL) {
      const int i = LVL_j[base + slot];
      const int p = PAR_c[i];
      const int row = e / 4, col = e - row * 4;
      const float* Ri = Rs + i * 9;
      const float g0 = G[p][row * 4 + 0], g1 = G[p][row * 4 + 1], g2 = G[p][row * 4 + 2];
      float v;
      if (col < 3) {
        v = g0 * Ri[col] + g1 * Ri[3 + col] + g2 * Ri[6 + col];
      } else {
        const float t0 = J[i * 3 + 0] - J[p * 3 + 0];
        const float t1 = J[i * 3 + 1] - J[p * 3 + 1];
        const float t2 = J[i * 3 + 2] - J[p * 3 + 2];
        v = g0 * t0 + g1 * t1 + g2 * t2 + G[p][row * 4 + 3];
      }
      G[i][e] = v;
    }
    __syncthreads();
  }
  if (tid < 3)
    j0s[tid] = W[WS_RSH + b * 3 + tid] - J[tid];
  __syncthreads();
  if (tid < 72) {
    const int j = tid / 3, d = tid % 3;
    out[OFF_NEWJ + (size_t)b * 72 + tid] = G[j][d * 4 + 3] + j0s[d];
  }
  for (int e = tid; e < 288; e += 256) {
    const int j = e / 12, rc = e - j * 12, row = rc / 4, col = rc - row * 4;
    float v = G[j][rc];
    if (col == 3)
      v -= G[j][row * 4 + 0] * J[j * 3 + 0] + G[j][row * 4 + 1] * J[j * 3 + 1] + G[j][row * 4 + 2] * J[j * 3 + 2];
    sA[j][rc] = v;
  }
  __syncthreads();
  unsigned short* at = (unsigned short*)(W + WS_AT) + (size_t)b * 768;
  for (int e = tid; e < 384; e += 256) {
    const int c = e >> 5, j = e & 31;
    float a = 0.f;
    if (j < 24) a = sA[j][c];
    else if (j == 24) a = ((c & 3) == 3) ? j0s[c >> 2] : 0.f;
    const unsigned short h = f2bf(a);
    const unsigned short l = f2bf(a - bf2f(h));
    at[c * 32 + j] = h;
    at[384 + c * 32 + j] = l;
  }
}

// ---------------------------------------------------------------------------
// K4 fused (512 threads / 8 waves): pose-GEMM + skinning, v_posed in LDS(bf16).
// Grid: x = vertex tile (16 verts = 48 n-rows), y = gender. All blocks work.
// ---------------------------------------------------------------------------
__launch_bounds__(512, 6)
__global__ void k4_fused(const float* __restrict__ pd, const float* __restrict__ vtemp,
                         const float* __restrict__ sdirs, const float* __restrict__ wts,
                         float* __restrict__ out, const float* __restrict__ W)
{
  __shared__ __align__(16) unsigned short bsm[48][BROW];
  __shared__ __align__(16) unsigned short vps[48][VROWB];
  __shared__ int s_ord[NB];

  const int tid = threadIdx.x;
  const int wave = tid >> 6, lane = tid & 63;
  const int g = blockIdx.y;
  const int nfrac = lane & 15;
  const int kq = (lane >> 4) * 8;
  const int tile = blockIdx.x;
  const int n0 = tile * 48;
  const int rbase = tile * 16;

  const int* cnt = (const int*)(W + WS_CNT);
  const int* ord = (const int*)(W + WS_ORD);
  const int nh = cnt[g];
  const int g0off = g ? cnt[0] : 0;
  if (nh <= 0) return;   // uniform, before any barrier

  if (tid < NB) s_ord[tid] = ord[tid];

  // ---- Phase 1: stage B tile — ALL loads issued, then all LDS writes ----
  const int nrows = (RD3 - n0 < 48) ? (RD3 - n0) : 48;
  const int nflat = nrows * KPD;                     // <= 9936
  const float* src = pd + ((size_t)g * RD3 + n0) * KPD;
  {
    float v[20];
#pragma unroll
    for (int i = 0; i < 5; i++) {
      const int e4 = (i * 512 + tid) * 4;
      if (e4 + 3 < nflat) {
        float t4[4];
        __builtin_memcpy(t4, src + e4, 16);
        v[i * 4 + 0] = t4[0]; v[i * 4 + 1] = t4[1]; v[i * 4 + 2] = t4[2]; v[i * 4 + 3] = t4[3];
      } else {
#pragma unroll
        for (int t = 0; t < 4; t++)
          v[i * 4 + t] = (e4 + t < nflat) ? src[e4 + t] : 0.f;
      }
    }
#pragma unroll
    for (int i = 0; i < 5; i++) {
      const int e4 = (i * 512 + tid) * 4;
#pragma unroll
      for (int t = 0; t < 4; t++) {
        const int fl = e4 + t;
        if (fl < nflat) bsm[fl / KPD][fl % KPD] = f2bf(v[i * 4 + t]);
      }
    }
  }
  // ---- extension cols (parallel single-element gathers) ----
  if (tid < 480) {
    const int r_ = tid / 10, kk = tid - r_ * 10;
    const int nr = (n0 + r_ < RD3) ? (n0 + r_) : (RD3 - 1);
    const int rr = nr / 3, dd = nr - rr * 3;
    bsm[r_][KPD + kk] = f2bf(sdirs[((size_t)(g * 10 + kk) * NR + rr) * 3 + dd]);
  }
  if (tid >= 464) {
    const int r_ = tid - 464;
    const int nr = (n0 + r_ < RD3) ? (n0 + r_) : (RD3 - 1);
    const int rr = nr / 3, dd = nr - rr * 3;
    bsm[r_][217] = f2bf(vtemp[((size_t)g * NR + rr) * 3 + dd]);
  }
  if (tid < 288) {
    const int r_ = tid / 6, kk = 218 + (tid - r_ * 6);
    bsm[r_][kk] = 0;
  }
  __syncthreads();

  // ---- Phase 2: GEMM -> vps (bf16). s outer (B-frag reuse), mt over waves ----
  const unsigned short* pfb = (const unsigned short*)(W + WS_PFB) + (size_t)g * 256 * 224;
  const int mtmax = (nh + 15) >> 4;
#pragma unroll
  for (int s = 0; s < 3; s++) {
    const unsigned short* bp = &bsm[s * 16 + nfrac][0];
    v8s bfr[7];
#pragma unroll
    for (int c = 0; c < 7; c++) bfr[c] = *(const v8s*)(bp + c * 32 + kq);
    for (int mt = wave; mt < mtmax; mt += 8) {
      const unsigned short* ap = pfb + (size_t)(mt * 16 + nfrac) * 224 + kq;
      v8s af[7];
#pragma unroll
      for (int c = 0; c < 7; c++) af[c] = *(const v8s*)(ap + c * 32);

      v4f acc0 = {0.f, 0.f, 0.f, 0.f};
      v4f acc1 = {0.f, 0.f, 0.f, 0.f};
      acc0 = __builtin_amdgcn_mfma_f32_16x16x32_bf16(af[0], bfr[0], acc0, 0, 0, 0);
      acc1 = __builtin_amdgcn_mfma_f32_16x16x32_bf16(af[1], bfr[1], acc1, 0, 0, 0);
      acc0 = __builtin_amdgcn_mfma_f32_16x16x32_bf16(af[2], bfr[2], acc0, 0, 0, 0);
      acc1 = __builtin_amdgcn_mfma_f32_16x16x32_bf16(af[3], bfr[3], acc1, 0, 0, 0);
      acc0 = __builtin_amdgcn_mfma_f32_16x16x32_bf16(af[4], bfr[4], acc0, 0, 0, 0);
      acc1 = __builtin_amdgcn_mfma_f32_16x16x32_bf16(af[5], bfr[5], acc1, 0, 0, 0);
      acc0 = __builtin_amdgcn_mfma_f32_16x16x32_bf16(af[6], bfr[6], acc0, 0, 0, 0);

      const int ln = s * 16 + nfrac;
      const int lm0 = mt * 16 + (lane >> 4) * 4;
#pragma unroll
      for (int j = 0; j < 4; j++)
        vps[ln][lm0 + j] = f2bf(acc0[j] + acc1[j]);
    }
  }
  __syncthreads();

  // ---- Phase 3: skinning, TWO batches per iteration (independent MLP) ----
  const int f = nfrac, q = lane >> 4;
  const int r = rbase + f;
  const int rc = (r < NR) ? r : (NR - 1);

  int vli = -1;
#pragma unroll
  for (int i = 0; i < 10; i++) if (r == VL_c[i]) vli = i;
  const int syj = (vli >= 0) ? SY_c[vli] : 0;

  v8s wh, wl;
  {
    union { v8s v; unsigned short s[8]; } H, L;
    if (q < 3) {
      float fw[8];
      __builtin_memcpy(fw, wts + ((size_t)g * NR + rc) * 24 + q * 8, 32);
#pragma unroll
      for (int t = 0; t < 8; t++) { H.s[t] = f2bf(fw[t]); L.s[t] = f2bf(fw[t] - bf2f(H.s[t])); }
    } else {
#pragma unroll
      for (int t = 0; t < 8; t++) { H.s[t] = (t == 0) ? 0x3F80 : 0; L.s[t] = 0; }
    }
    wh = H.v; wl = L.v;
  }

  const unsigned short* at = (const unsigned short*)(W + WS_AT);
  const int fragoff = f * 32 + q * 8;

  for (int lm = wave; lm < nh; lm += 16) {
    const int lmB = lm + 8;
    const bool hasB = (lmB < nh);
    const int lmBc = hasB ? lmB : lm;
    const int b1 = s_ord[g0off + lm];
    const int b2 = s_ord[g0off + lmBc];
    // both operand sets loaded up-front (independent)
    const v8s ah1 = *(const v8s*)(at + (size_t)b1 * 768 + fragoff);
    const v8s al1 = *(const v8s*)(at + (size_t)b1 * 768 + 384 + fragoff);
    const v8s ah2 = *(const v8s*)(at + (size_t)b2 * 768 + fragoff);
    const v8s al2 = *(const v8s*)(at + (size_t)b2 * 768 + 384 + fragoff);
    const float vx1 = bf2f(vps[f * 3 + 0][lm]);
    const float vy1 = bf2f(vps[f * 3 + 1][lm]);
    const float vz1 = bf2f(vps[f * 3 + 2][lm]);
    const float vx2 = bf2f(vps[f * 3 + 0][lmBc]);
    const float vy2 = bf2f(vps[f * 3 + 1][lmBc]);
    const float vz2 = bf2f(vps[f * 3 + 2][lmBc]);

    v4f accA = {0.f, 0.f, 0.f, 0.f};
    v4f accB = {0.f, 0.f, 0.f, 0.f};
    accA = __builtin_amdgcn_mfma_f32_16x16x32_bf16(ah1, wh, accA, 0, 0, 0);
    accB = __builtin_amdgcn_mfma_f32_16x16x32_bf16(ah2, wh, accB, 0, 0, 0);
    accA = __builtin_amdgcn_mfma_f32_16x16x32_bf16(ah1, wl, accA, 0, 0, 0);
    accB = __builtin_amdgcn_mfma_f32_16x16x32_bf16(ah2, wl, accB, 0, 0, 0);
    accA = __builtin_amdgcn_mfma_f32_16x16x32_bf16(al1, wh, accA, 0, 0, 0);
    accB = __builtin_amdgcn_mfma_f32_16x16x32_bf16(al2, wh, accB, 0, 0, 0);

    const float o1 = accA[0] * vx1 + accA[1] * vy1 + accA[2] * vz1 + accA[3];
    const float o2 = accB[0] * vx2 + accB[1] * vy2 + accB[2] * vz2 + accB[3];
    if (q < 3 && r < NR) {
      out[OFF_VERTS + ((size_t)b1 * NR + r) * 3 + q] = o1;
      if (hasB) out[OFF_VERTS + ((size_t)b2 * NR + r) * 3 + q] = o2;
      if (vli >= 0) {
        out[OFF_VRED + ((size_t)b1 * 10 + vli) * 3 + q] = o1;
        out[OFF_VOFF + ((size_t)b1 * 10 + vli) * 3 + q] =
            o1 - out[OFF_NEWJ + (size_t)b1 * 72 + syj * 3 + q];
        if (hasB) {
          out[OFF_VRED + ((size_t)b2 * 10 + vli) * 3 + q] = o2;
          out[OFF_VOFF + ((size_t)b2 * 10 + vli) * 3 + q] =
              o2 - out[OFF_NEWJ + (size_t)b2 * 72 + syj * 3 + q];
        }
      }
    }
  }
}

// ---------------------------------------------------------------------------
extern "C" void kernel_launch(void* const* d_in, const int* in_sizes, int n_in,
                              void* d_out, int out_size, void* d_ws, size_t ws_size,
                              hipStream_t stream)
{
  const float* x   = (const float*)d_in[0];
  const float* gen = (const float*)d_in[1];
  const float* vt  = (const float*)d_in[2];
  const float* sd  = (const float*)d_in[3];
  const float* jr  = (const float*)d_in[4];
  const float* pd  = (const float*)d_in[5];
  const float* wt  = (const float*)d_in[6];
  float* out = (float*)d_out;
  float* W   = (float*)d_ws;

  kA_front<<<NB + 2 * 24 * K2C, 256, 0, stream>>>(x, gen, vt, sd, jr, out, W);
  kB_mid<<<512 + NB, 256, 0, stream>>>(out, W);
  k4_fused<<<dim3(NT4, 2), 512, 0, stream>>>(pd, vt, sd, wt, out, W);
}

// Round 15
// 75.389 us; speedup vs baseline: 1.0751x; 1.0337x over previous
//
#include <hip/hip_runtime.h>
#include <hip/hip_bf16.h>

// ---------------------------------------------------------------------------
// MeshEstimator (SMPL-like) forward.  B=256, R=6890, 24 joints, 207 pose dims.
// R14 -> R15: k4_fused latency fix via BARRIER-FENCED prefetch (compiler
// cannot sink global loads across __syncthreads): per-wave A-fragments (one
// mt per wave when mtmax<=8) + weight hi/lo fragments loaded at kernel top,
// completing under phase-1 staging. Phase 2 re-nested mt-outer/s-inner so A
// loads once per mt (was 3x). Phases 1/3 otherwise as R14.
// ---------------------------------------------------------------------------

#define NB 256
#define NR 6890
#define NJ 24
#define RD3 (NR*3)  // 20670
#define KPD 207
#define K2C 8       // k2 r-chunks
#define K2R 862     // rows per chunk
#define NT4 431     // vertex-tiles of 16 (431*16 = 6896 >= 6890)
#define BROW 232    // bsm row stride in bf16 (464B)
#define VROWB 264   // vps row stride in bf16 (528B)

// ---- output offsets (floats) ----
#define OFF_BETAS 0
#define OFF_POSE  2560
#define OFF_RSH   20992
#define OFF_RA    21760
#define OFF_VERTS 23296
#define OFF_VRED  5314816
#define OFF_NEWJ  5322496
#define OFF_VOFF  5340928

// ---- workspace offsets (floats) ----
#define WS_RS    0         // Rs: 256*24*9 = 55296
#define WS_PF    55296     // pose_feat: 256*207 = 52992 -> ends 108288
#define WS_BETA  108288    // 2560
#define WS_RSH   110848    // 768
#define WS_GI    111616    // 256 ints
#define WS_ORD   111872    // 256 ints
#define WS_CNT   112128    // 2 ints (+2 pad)
#define WS_PFB   112904    // bf16 A-matrix: 2*256*224 ushort = 57344 floats
#define WS_AT    170248    // packed At per batch: hi[12][32]+lo[12][32] ushort

typedef short v8s __attribute__((ext_vector_type(8)));
typedef float v4f __attribute__((ext_vector_type(4)));

__constant__ int PAR_c[24] = {0,0,0,0,1,2,3,4,5,6,7,8,9,9,9,12,13,14,16,17,18,19,20,21};
__constant__ int VL_c[10]  = {1325,336,1032,4515,1374,4848,1739,5209,1960,5423};
__constant__ int SY_c[10]  = {3,15,4,5,7,8,18,19,20,21};
__constant__ int LVL_j[23]  = {1,2,3, 4,5,6, 7,8,9, 10,11,12,13,14, 15,16,17, 18,19, 20,21, 22,23};
__constant__ int LVL_off[9] = {0,3,6,9,14,17,19,21,23};

__constant__ float BLO[72] = {
  -0.5933865286111969f, -6.283185307179586f, -1.215762200416361f,
  -1.5793940868065197f, -0.5881754611f, -0.5323249722f,
  -1.5793940868065197f, -0.5689768556f, -0.6736965222f,
  -1.0471975511965976f, -0.08726646259971647f, -0.08726646259971647f,
  -0.02268926111f, -0.01f, -0.01f,
  -0.02268926111f, -0.01f, -0.01f,
  -1.0471975511965976f, -0.08726646259971647f, -0.08726646259971647f,
  -0.5235987755982988f, -0.5235987755982988f, -0.5235987755982988f,
  -0.5235987755982988f, -0.5235987755982988f, -0.5235987755982988f,
  -1.0471975511965976f, -0.08726646259971647f, -0.08726646259971647f,
  -0.01f, -0.01f, -0.01f, -0.01f, -0.01f, -0.01f,
  -1.0471975511965976f, -0.08726646259971647f, -0.08726646259971647f,
  (float)(-1.551596394/3.0), (float)(-2.455676183/3.0), (float)(-1.570795/3.0),
  (float)(-1.551596394/3.0), (float)(-0.7627082389/3.0), (float)(-2.188641033/3.0),
  -1.0471975511965976f, -0.08726646259971647f, -0.08726646259971647f,
  (float)(-1.551596394*2.0/3.0), (float)(-2.455676183*2.0/3.0), (float)(-1.570795*2.0/3.0),
  (float)(-1.551596394*2.0/3.0), (float)(-0.7627082389*2.0/3.0), (float)(-2.188641033*2.0/3.0),
  -0.01f, -2.570867817f, -0.01f, -0.01f, -0.04799651389f, -0.01f,
  -0.5235987755982988f, -0.5235987755982988f, -0.5235987755982988f,
  -0.5235987755982988f, -0.5235987755982988f, -0.5235987755982988f,
  -0.01f, -0.01f, -0.01f, -0.01f, -0.01f, -0.01f
};
__constant__ float BHI[72] = {
  0.5933865286111969f, 6.283185307179586f, 1.215762200416361f,
  0.3097956806f, 0.5689768556f, 0.6736965222f,
  0.3097956806f, 0.5881754611f, 0.5323249722f,
  1.0471975511965976f, 0.08726646259971647f, 0.08726646259971647f,
  2.441713561f, 0.01f, 0.01f,
  2.441713561f, 0.01f, 0.01f,
  1.0471975511965976f, 0.08726646259971647f, 0.08726646259971647f,
  0.5235987755982988f, 0.5235987755982988f, 0.5235987755982988f,
  0.5235987755982988f, 0.5235987755982988f, 0.5235987755982988f,
  1.0471975511965976f, 0.08726646259971647f, 0.08726646259971647f,
  0.01f, 0.01f, 0.01f, 0.01f, 0.01f, 0.01f,
  1.0471975511965976f, 0.08726646259971647f, 0.08726646259971647f,
  (float)(2.206094311/3.0), (float)(0.7627082389/3.0), (float)(2.188641033/3.0),
  (float)(2.206094311/3.0), (float)(2.455676183/3.0), (float)(1.570795/3.0),
  1.0471975511965976f, 0.08726646259971647f, 0.08726646259971647f,
  (float)(2.206094311*2.0/3.0), (float)(0.7627082389*2.0/3.0), (float)(2.188641033*2.0/3.0),
  (float)(2.206094311*2.0/3.0), (float)(2.455676183*2.0/3.0), (float)(1.570795*2.0/3.0),
  0.01f, 0.04799651389f, 0.01f, 0.01f, 2.570867817f, 0.01f,
  0.5235987755982988f, 0.5235987755982988f, 0.5235987755982988f,
  0.5235987755982988f, 0.5235987755982988f, 0.5235987755982988f,
  0.01f, 0.01f, 0.01f, 0.01f, 0.01f, 0.01f
};

__device__ __forceinline__ unsigned short f2bf(float f) {
  union { float f; unsigned u; } c; c.f = f;
  const unsigned u = c.u + 0x7FFFu + ((c.u >> 16) & 1u);   // RNE
  return (unsigned short)(u >> 16);
}
__device__ __forceinline__ float bf2f(unsigned short h) {
  union { unsigned u; float f; } c; c.u = (unsigned)h << 16; return c.f;
}

// ---------------------------------------------------------------------------
// kA: block-partitioned merge of k1 (per-batch pose, 256 blocks) and
// k2 (joint-regressor partials, 384 blocks). 256 threads.
// ---------------------------------------------------------------------------
__global__ void kA_front(const float* __restrict__ x, const float* __restrict__ gen,
                         const float* __restrict__ vtemp, const float* __restrict__ sdirs,
                         const float* __restrict__ jreg,
                         float* __restrict__ out, float* __restrict__ W)
{
  const int bid = blockIdx.x;
  const int tid = threadIdx.x;

  if (bid < NB) {
    const int b = bid;
    const float* xb = x + b * 88;
    if (tid < 24) {
      const int j = tid;
      float t[3];
      if (j == 0) {
        t[0] = atan2f(xb[16], xb[13]);
        t[1] = atan2f(xb[17], xb[14]);
        t[2] = atan2f(xb[18], xb[15]);
      } else {
        t[0] = xb[19 + (j - 1) * 3 + 0];
        t[1] = xb[19 + (j - 1) * 3 + 1];
        t[2] = xb[19 + (j - 1) * 3 + 2];
      }
#pragma unroll
      for (int c = 0; c < 3; c++) {
        const int pi = j * 3 + c;
        const float lo = 2.f * BLO[pi], hi = 2.f * BHI[pi];
        const float mean = 0.5f * (lo + hi);
        const float scale = 2.f / fabsf(lo - hi);
        const float v = tanhf((t[c] - mean) * scale) / scale + mean;
        t[c] = v;
        out[OFF_POSE + b * 72 + pi] = v;
      }
      const float a0 = t[0] + 1e-8f, a1 = t[1] + 1e-8f, a2 = t[2] + 1e-8f;
      const float ang = sqrtf(a0 * a0 + a1 * a1 + a2 * a2);
      const float half = 0.5f * ang;
      const float sh = sinf(half), ch = cosf(half);
      const float inv = sh / ang;
      float qw = ch, qx = t[0] * inv, qy = t[1] * inv, qz = t[2] * inv;
      const float nn = sqrtf(qw * qw + qx * qx + qy * qy + qz * qz);
      qw /= nn; qx /= nn; qy /= nn; qz /= nn;
      float R[9];
      R[0] = 1.f - 2.f * (qy * qy + qz * qz); R[1] = 2.f * (qx * qy - qw * qz); R[2] = 2.f * (qx * qz + qw * qy);
      R[3] = 2.f * (qx * qy + qw * qz); R[4] = 1.f - 2.f * (qx * qx + qz * qz); R[5] = 2.f * (qy * qz - qw * qx);
      R[6] = 2.f * (qx * qz - qw * qy); R[7] = 2.f * (qy * qz + qw * qx); R[8] = 1.f - 2.f * (qx * qx + qy * qy);
      float* rsw = W + WS_RS + (size_t)(b * 24 + j) * 9;
#pragma unroll
      for (int e = 0; e < 9; e++) rsw[e] = R[e];
      if (j >= 1) {
        float* pfw = W + WS_PF + (size_t)b * 207 + (j - 1) * 9;
#pragma unroll
        for (int e = 0; e < 9; e++)
          pfw[e] = R[e] - ((e == 0 || e == 4 || e == 8) ? 1.f : 0.f);
      }
    } else if (tid < 34) {
      const int k = tid - 24;
      const float v = tanhf(xb[k] / 3.0f) * 3.0f;
      out[OFF_BETAS + b * 10 + k] = v;
      W[WS_BETA + b * 10 + k] = v;
    } else if (tid == 34) {
      const float r0 = xb[10] + (0.6f - 0.286f);
      const float r1 = xb[11] + (1.2f - 0.286f);
      const float r2 = xb[12] + 0.1f;
      out[OFF_RSH + b * 3 + 0] = r0; out[OFF_RSH + b * 3 + 1] = r1; out[OFF_RSH + b * 3 + 2] = r2;
      W[WS_RSH + b * 3 + 0] = r0; W[WS_RSH + b * 3 + 1] = r1; W[WS_RSH + b * 3 + 2] = r2;
#pragma unroll
      for (int k2 = 0; k2 < 6; k2++) out[OFF_RA + b * 6 + k2] = xb[13 + k2];
    } else if (tid == 35) {
      ((int*)(W + WS_GI))[b] = (gen[b * 2 + 1] > gen[b * 2 + 0]) ? 1 : 0;
    }
    return;
  }

  // ---------------- k2 part ----------------
  const int kb = bid - NB;
  const int c = kb % K2C, j = (kb / K2C) % 24, g = kb / (K2C * 24);
  const int r0 = c * K2R;
  int r1 = r0 + K2R; if (r1 > NR) r1 = NR;
  const float* vtg = vtemp + (size_t)g * NR * 3;
  const float* sdg = sdirs + (size_t)g * 10 * NR * 3;
  const float* jrg = jreg + (size_t)g * NR * 24;
  float acc[33];
#pragma unroll
  for (int e = 0; e < 33; e++) acc[e] = 0.f;
  for (int r = r0 + tid; r < r1; r += 256) {
    const float w = jrg[r * 24 + j];
    acc[0] += vtg[r * 3 + 0] * w;
    acc[1] += vtg[r * 3 + 1] * w;
    acc[2] += vtg[r * 3 + 2] * w;
#pragma unroll
    for (int k = 0; k < 10; k++) {
      const float* s = sdg + ((size_t)k * NR + r) * 3;
      acc[3 + k * 3 + 0] += s[0] * w;
      acc[3 + k * 3 + 1] += s[1] * w;
      acc[3 + k * 3 + 2] += s[2] * w;
    }
  }
  __shared__ float red[4][33];
  const int lane = tid & 63, wv = tid >> 6;
#pragma unroll
  for (int e = 0; e < 33; e++) {
    float v = acc[e];
    v += __shfl_down(v, 32); v += __shfl_down(v, 16); v += __shfl_down(v, 8);
    v += __shfl_down(v, 4);  v += __shfl_down(v, 2);  v += __shfl_down(v, 1);
    if (lane == 0) red[wv][e] = v;
  }
  __syncthreads();
  if (tid < 33) {
    const int e = tid;
    out[OFF_VERTS + (size_t)(((g * 24 + j) * K2C + c) * 33 + e)] =
        red[0][e] + red[1][e] + red[2][e] + red[3][e];
  }
}

// ---------------------------------------------------------------------------
// kB: merge of (in-block gender compaction + PFB pack, 512 blocks) and
// k3 kinematic chain (256 blocks). 256 threads.
// ---------------------------------------------------------------------------
__global__ void kB_mid(float* __restrict__ out, float* __restrict__ W)
{
  const int bid = blockIdx.x;
  const int tid = threadIdx.x;

  if (bid < 512) {
    __shared__ int s_ord[NB];
    __shared__ int s_c0[4];
    const int gib = ((const int*)(W + WS_GI))[tid];
    const int lane = tid & 63, wvi = tid >> 6;
    const unsigned long long b0 = __ballot(gib == 0);
    if (lane == 0) s_c0[wvi] = __popcll(b0);
    __syncthreads();
    const int t0 = s_c0[0] + s_c0[1] + s_c0[2] + s_c0[3];
    int off0 = 0, off1 = t0;
    for (int w = 0; w < wvi; w++) { off0 += s_c0[w]; off1 += 64 - s_c0[w]; }
    const unsigned long long ltm = (1ull << lane) - 1ull;
    const int rr0 = __popcll(b0 & ltm);
    const int rr1 = lane - rr0;
    if (gib == 0) s_ord[off0 + rr0] = tid;
    else          s_ord[off1 + rr1] = tid;
    __syncthreads();

    if (bid == 0) {
      ((int*)(W + WS_ORD))[tid] = s_ord[tid];
      if (tid == 0) { ((int*)(W + WS_CNT))[0] = t0; ((int*)(W + WS_CNT))[1] = NB - t0; }
    }

    const int g = bid >> 8, m = bid & 255;
    const int n_g = g ? (NB - t0) : t0;
    const int g0off = g ? t0 : 0;
    if (tid < 224) {
      float v = 0.f;
      if (m < n_g) {
        const int b = s_ord[g0off + m];
        if (tid < KPD)        v = W[WS_PF + (size_t)b * KPD + tid];
        else if (tid < 217)   v = W[WS_BETA + b * 10 + (tid - KPD)];
        else if (tid == 217)  v = 1.f;
      }
      ((unsigned short*)(W + WS_PFB))[((size_t)g * 256 + m) * 224 + tid] = f2bf(v);
    }
    return;
  }

  // -------- k3 part: b = bid - 512 --------
  const int b = bid - 512;
  __shared__ float J[72];
  __shared__ float G[24][12];
  __shared__ float sA[24][12];
  __shared__ float j0s[3];
  const int gi = ((const int*)(W + WS_GI))[b];
  float bb[10];
#pragma unroll
  for (int k = 0; k < 10; k++) bb[k] = W[WS_BETA + b * 10 + k];

  if (tid < 72) {
    const int j = tid / 3, d = tid % 3;
    float v = 0.f;
#pragma unroll
    for (int c = 0; c < K2C; c++) {
      const float* P = out + OFF_VERTS + (size_t)(((gi * 24 + j) * K2C + c) * 33);
      float s = P[d];
#pragma unroll
      for (int k = 0; k < 10; k++) s += bb[k] * P[3 + k * 3 + d];
      v += s;
    }
    J[tid] = v;
  }
  __syncthreads();
  const float* Rs = W + WS_RS + (size_t)b * 216;
  if (tid < 12) {
    const int row = tid / 4, col = tid % 4;
    G[0][tid] = (col < 3) ? Rs[row * 3 + col] : J[row];
  }
  __syncthreads();
#pragma unroll
  for (int L = 0; L < 8; L++) {
    const int base = LVL_off[L];
    const int cntL = LVL_off[L + 1] - base;
    const int slot = tid / 12, e = tid - slot * 12;
    if (slot < cntL) {
      const int i = LVL_j[base + slot];
      const int p = PAR_c[i];
      const int row = e / 4, col = e - row * 4;
      const float* Ri = Rs + i * 9;
      const float g0 = G[p][row * 4 + 0], g1 = G[p][row * 4 + 1], g2 = G[p][row * 4 + 2];
      float v;
      if (col < 3) {
        v = g0 * Ri[col] + g1 * Ri[3 + col] + g2 * Ri[6 + col];
      } else {
        const float t0 = J[i * 3 + 0] - J[p * 3 + 0];
        const float t1 = J[i * 3 + 1] - J[p * 3 + 1];
        const float t2 = J[i * 3 + 2] - J[p * 3 + 2];
        v = g0 * t0 + g1 * t1 + g2 * t2 + G[p][row * 4 + 3];
      }
      G[i][e] = v;
    }
    __syncthreads();
  }
  if (tid < 3)
    j0s[tid] = W[WS_RSH + b * 3 + tid] - J[tid];
  __syncthreads();
  if (tid < 72) {
    const int j = tid / 3, d = tid % 3;
    out[OFF_NEWJ + (size_t)b * 72 + tid] = G[j][d * 4 + 3] + j0s[d];
  }
  for (int e = tid; e < 288; e += 256) {
    const int j = e / 12, rc = e - j * 12, row = rc / 4, col = rc - row * 4;
    float v = G[j][rc];
    if (col == 3)
      v -= G[j][row * 4 + 0] * J[j * 3 + 0] + G[j][row * 4 + 1] * J[j * 3 + 1] + G[j][row * 4 + 2] * J[j * 3 + 2];
    sA[j][rc] = v;
  }
  __syncthreads();
  unsigned short* at = (unsigned short*)(W + WS_AT) + (size_t)b * 768;
  for (int e = tid; e < 384; e += 256) {
    const int c = e >> 5, j = e & 31;
    float a = 0.f;
    if (j < 24) a = sA[j][c];
    else if (j == 24) a = ((c & 3) == 3) ? j0s[c >> 2] : 0.f;
    const unsigned short h = f2bf(a);
    const unsigned short l = f2bf(a - bf2f(h));
    at[c * 32 + j] = h;
    at[384 + c * 32 + j] = l;
  }
}

// ---------------------------------------------------------------------------
// K4 fused (512 threads / 8 waves): pose-GEMM + skinning, v_posed in LDS(bf16).
// Barrier-fenced prefetch: af0 (this wave's A-fragments) + weight fragments
// loaded BEFORE phase-1 staging; the __syncthreads completes them for free.
// ---------------------------------------------------------------------------
__launch_bounds__(512, 6)
__global__ void k4_fused(const float* __restrict__ pd, const float* __restrict__ vtemp,
                         const float* __restrict__ sdirs, const float* __restrict__ wts,
                         float* __restrict__ out, const float* __restrict__ W)
{
  __shared__ __align__(16) unsigned short bsm[48][BROW];
  __shared__ __align__(16) unsigned short vps[48][VROWB];
  __shared__ int s_ord[NB];

  const int tid = threadIdx.x;
  const int wave = tid >> 6, lane = tid & 63;
  const int g = blockIdx.y;
  const int nfrac = lane & 15;
  const int kq = (lane >> 4) * 8;
  const int tile = blockIdx.x;
  const int n0 = tile * 48;
  const int rbase = tile * 16;

  const int* cnt = (const int*)(W + WS_CNT);
  const int* ord = (const int*)(W + WS_ORD);
  const int nh = cnt[g];
  const int g0off = g ? cnt[0] : 0;
  if (nh <= 0) return;   // uniform, before any barrier

  const int mtmax = (nh + 15) >> 4;
  const unsigned short* pfb = (const unsigned short*)(W + WS_PFB) + (size_t)g * 256 * 224;

  // ===== barrier-fenced prefetch #1: this wave's first A-fragment set =====
  v8s af0[7];
  if (wave < mtmax) {
    const unsigned short* ap0 = pfb + (size_t)(wave * 16 + nfrac) * 224 + kq;
#pragma unroll
    for (int c = 0; c < 7; c++) af0[c] = *(const v8s*)(ap0 + c * 32);
  } else {
#pragma unroll
    for (int c = 0; c < 7; c++) af0[c] = (v8s){0,0,0,0,0,0,0,0};
  }

  // ===== barrier-fenced prefetch #2: weight fragments (phase 3) =====
  const int f = nfrac, q = lane >> 4;
  const int r = rbase + f;
  const int rc = (r < NR) ? r : (NR - 1);
  v8s wh, wl;
  {
    union { v8s v; unsigned short s[8]; } H, L;
    if (q < 3) {
      float fw[8];
      __builtin_memcpy(fw, wts + ((size_t)g * NR + rc) * 24 + q * 8, 32);
#pragma unroll
      for (int t = 0; t < 8; t++) { H.s[t] = f2bf(fw[t]); L.s[t] = f2bf(fw[t] - bf2f(H.s[t])); }
    } else {
#pragma unroll
      for (int t = 0; t < 8; t++) { H.s[t] = (t == 0) ? 0x3F80 : 0; L.s[t] = 0; }
    }
    wh = H.v; wl = L.v;
  }

  if (tid < NB) s_ord[tid] = ord[tid];

  // ---- Phase 1: stage B tile — all loads issued, then all LDS writes ----
  const int nrows = (RD3 - n0 < 48) ? (RD3 - n0) : 48;
  const int nflat = nrows * KPD;                     // <= 9936
  const float* src = pd + ((size_t)g * RD3 + n0) * KPD;
  {
    float v[20];
#pragma unroll
    for (int i = 0; i < 5; i++) {
      const int e4 = (i * 512 + tid) * 4;
      if (e4 + 3 < nflat) {
        float t4[4];
        __builtin_memcpy(t4, src + e4, 16);
        v[i * 4 + 0] = t4[0]; v[i * 4 + 1] = t4[1]; v[i * 4 + 2] = t4[2]; v[i * 4 + 3] = t4[3];
      } else {
#pragma unroll
        for (int t = 0; t < 4; t++)
          v[i * 4 + t] = (e4 + t < nflat) ? src[e4 + t] : 0.f;
      }
    }
#pragma unroll
    for (int i = 0; i < 5; i++) {
      const int e4 = (i * 512 + tid) * 4;
#pragma unroll
      for (int t = 0; t < 4; t++) {
        const int fl = e4 + t;
        if (fl < nflat) bsm[fl / KPD][fl % KPD] = f2bf(v[i * 4 + t]);
      }
    }
  }
  if (tid < 480) {
    const int r_ = tid / 10, kk = tid - r_ * 10;
    const int nr = (n0 + r_ < RD3) ? (n0 + r_) : (RD3 - 1);
    const int rr = nr / 3, dd = nr - rr * 3;
    bsm[r_][KPD + kk] = f2bf(sdirs[((size_t)(g * 10 + kk) * NR + rr) * 3 + dd]);
  }
  if (tid >= 464) {
    const int r_ = tid - 464;
    const int nr = (n0 + r_ < RD3) ? (n0 + r_) : (RD3 - 1);
    const int rr = nr / 3, dd = nr - rr * 3;
    bsm[r_][217] = f2bf(vtemp[((size_t)g * NR + rr) * 3 + dd]);
  }
  if (tid < 288) {
    const int r_ = tid / 6, kk = 218 + (tid - r_ * 6);
    bsm[r_][kk] = 0;
  }
  __syncthreads();   // <- fences the prefetches: af0/wh/wl now in registers

  // ---- Phase 2: GEMM -> vps (bf16). mt outer (A once), s inner ----
  if (wave < mtmax) {
    const int mt = wave;
#pragma unroll
    for (int s = 0; s < 3; s++) {
      const unsigned short* bp = &bsm[s * 16 + nfrac][0];
      v8s bfr[7];
#pragma unroll
      for (int c = 0; c < 7; c++) bfr[c] = *(const v8s*)(bp + c * 32 + kq);

      v4f acc0 = {0.f, 0.f, 0.f, 0.f};
      v4f acc1 = {0.f, 0.f, 0.f, 0.f};
      acc0 = __builtin_amdgcn_mfma_f32_16x16x32_bf16(af0[0], bfr[0], acc0, 0, 0, 0);
      acc1 = __builtin_amdgcn_mfma_f32_16x16x32_bf16(af0[1], bfr[1], acc1, 0, 0, 0);
      acc0 = __builtin_amdgcn_mfma_f32_16x16x32_bf16(af0[2], bfr[2], acc0, 0, 0, 0);
      acc1 = __builtin_amdgcn_mfma_f32_16x16x32_bf16(af0[3], bfr[3], acc1, 0, 0, 0);
      acc0 = __builtin_amdgcn_mfma_f32_16x16x32_bf16(af0[4], bfr[4], acc0, 0, 0, 0);
      acc1 = __builtin_amdgcn_mfma_f32_16x16x32_bf16(af0[5], bfr[5], acc1, 0, 0, 0);
      acc0 = __builtin_amdgcn_mfma_f32_16x16x32_bf16(af0[6], bfr[6], acc0, 0, 0, 0);

      const int ln = s * 16 + nfrac;
      const int lm0 = mt * 16 + (lane >> 4) * 4;
#pragma unroll
      for (int j = 0; j < 4; j++)
        vps[ln][lm0 + j] = f2bf(acc0[j] + acc1[j]);
    }
  }
  // rare general case: mtmax > 8 (one gender holds >128 batches)
  for (int mt = wave + 8; mt < mtmax; mt += 8) {
    const unsigned short* ap = pfb + (size_t)(mt * 16 + nfrac) * 224 + kq;
    v8s af[7];
#pragma unroll
    for (int c = 0; c < 7; c++) af[c] = *(const v8s*)(ap + c * 32);
#pragma unroll
    for (int s = 0; s < 3; s++) {
      const unsigned short* bp = &bsm[s * 16 + nfrac][0];
      v8s bfr[7];
#pragma unroll
      for (int c = 0; c < 7; c++) bfr[c] = *(const v8s*)(bp + c * 32 + kq);
      v4f acc0 = {0.f, 0.f, 0.f, 0.f};
      v4f acc1 = {0.f, 0.f, 0.f, 0.f};
      acc0 = __builtin_amdgcn_mfma_f32_16x16x32_bf16(af[0], bfr[0], acc0, 0, 0, 0);
      acc1 = __builtin_amdgcn_mfma_f32_16x16x32_bf16(af[1], bfr[1], acc1, 0, 0, 0);
      acc0 = __builtin_amdgcn_mfma_f32_16x16x32_bf16(af[2], bfr[2], acc0, 0, 0, 0);
      acc1 = __builtin_amdgcn_mfma_f32_16x16x32_bf16(af[3], bfr[3], acc1, 0, 0, 0);
      acc0 = __builtin_amdgcn_mfma_f32_16x16x32_bf16(af[4], bfr[4], acc0, 0, 0, 0);
      acc1 = __builtin_amdgcn_mfma_f32_16x16x32_bf16(af[5], bfr[5], acc1, 0, 0, 0);
      acc0 = __builtin_amdgcn_mfma_f32_16x16x32_bf16(af[6], bfr[6], acc0, 0, 0, 0);
      const int ln = s * 16 + nfrac;
      const int lm0 = mt * 16 + (lane >> 4) * 4;
#pragma unroll
      for (int j = 0; j < 4; j++)
        vps[ln][lm0 + j] = f2bf(acc0[j] + acc1[j]);
    }
  }
  __syncthreads();

  // ---- Phase 3: skinning, two batches per iteration ----
  int vli = -1;
#pragma unroll
  for (int i = 0; i < 10; i++) if (r == VL_c[i]) vli = i;
  const int syj = (vli >= 0) ? SY_c[vli] : 0;

  const unsigned short* at = (const unsigned short*)(W + WS_AT);
  const int fragoff = f * 32 + q * 8;

  for (int lm = wave; lm < nh; lm += 16) {
    const int lmB = lm + 8;
    const bool hasB = (lmB < nh);
    const int lmBc = hasB ? lmB : lm;
    const int b1 = s_ord[g0off + lm];
    const int b2 = s_ord[g0off + lmBc];
    const v8s ah1 = *(const v8s*)(at + (size_t)b1 * 768 + fragoff);
    const v8s al1 = *(const v8s*)(at + (size_t)b1 * 768 + 384 + fragoff);
    const v8s ah2 = *(const v8s*)(at + (size_t)b2 * 768 + fragoff);
    const v8s al2 = *(const v8s*)(at + (size_t)b2 * 768 + 384 + fragoff);
    const float vx1 = bf2f(vps[f * 3 + 0][lm]);
    const float vy1 = bf2f(vps[f * 3 + 1][lm]);
    const float vz1 = bf2f(vps[f * 3 + 2][lm]);
    const float vx2 = bf2f(vps[f * 3 + 0][lmBc]);
    const float vy2 = bf2f(vps[f * 3 + 1][lmBc]);
    const float vz2 = bf2f(vps[f * 3 + 2][lmBc]);

    v4f accA = {0.f, 0.f, 0.f, 0.f};
    v4f accB = {0.f, 0.f, 0.f, 0.f};
    accA = __builtin_amdgcn_mfma_f32_16x16x32_bf16(ah1, wh, accA, 0, 0, 0);
    accB = __builtin_amdgcn_mfma_f32_16x16x32_bf16(ah2, wh, accB, 0, 0, 0);
    accA = __builtin_amdgcn_mfma_f32_16x16x32_bf16(ah1, wl, accA, 0, 0, 0);
    accB = __builtin_amdgcn_mfma_f32_16x16x32_bf16(ah2, wl, accB, 0, 0, 0);
    accA = __builtin_amdgcn_mfma_f32_16x16x32_bf16(al1, wh, accA, 0, 0, 0);
    accB = __builtin_amdgcn_mfma_f32_16x16x32_bf16(al2, wh, accB, 0, 0, 0);

    const float o1 = accA[0] * vx1 + accA[1] * vy1 + accA[2] * vz1 + accA[3];
    const float o2 = accB[0] * vx2 + accB[1] * vy2 + accB[2] * vz2 + accB[3];
    if (q < 3 && r < NR) {
      out[OFF_VERTS + ((size_t)b1 * NR + r) * 3 + q] = o1;
      if (hasB) out[OFF_VERTS + ((size_t)b2 * NR + r) * 3 + q] = o2;
      if (vli >= 0) {
        out[OFF_VRED + ((size_t)b1 * 10 + vli) * 3 + q] = o1;
        out[OFF_VOFF + ((size_t)b1 * 10 + vli) * 3 + q] =
            o1 - out[OFF_NEWJ + (size_t)b1 * 72 + syj * 3 + q];
        if (hasB) {
          out[OFF_VRED + ((size_t)b2 * 10 + vli) * 3 + q] = o2;
          out[OFF_VOFF + ((size_t)b2 * 10 + vli) * 3 + q] =
              o2 - out[OFF_NEWJ + (size_t)b2 * 72 + syj * 3 + q];
        }
      }
    }
  }
}

// ---------------------------------------------------------------------------
extern "C" void kernel_launch(void* const* d_in, const int* in_sizes, int n_in,
                              void* d_out, int out_size, void* d_ws, size_t ws_size,
                              hipStream_t stream)
{
  const float* x   = (const float*)d_in[0];
  const float* gen = (const float*)d_in[1];
  const float* vt  = (const float*)d_in[2];
  const float* sd  = (const float*)d_in[3];
  const float* jr  = (const float*)d_in[4];
  const float* pd  = (const float*)d_in[5];
  const float* wt  = (const float*)d_in[6];
  float* out = (float*)d_out;
  float* W   = (float*)d_ws;

  kA_front<<<NB + 2 * 24 * K2C, 256, 0, stream>>>(x, gen, vt, sd, jr, out, W);
  kB_mid<<<512 + NB, 256, 0, stream>>>(out, W);
  k4_fused<<<dim3(NT4, 2), 512, 0, stream>>>(pd, vt, sd, wt, out, W);
}

// Round 16
// 68.445 us; speedup vs baseline: 1.1841x; 1.1015x over previous
//
#include <hip/hip_runtime.h>
#include <hip/hip_bf16.h>

// ---------------------------------------------------------------------------
// MeshEstimator (SMPL-like) forward.  B=256, R=6890, 24 joints, 207 pose dims.
// R15 -> R16: remove ALL spill pressure from k4_fused (R15's af0 hoist spilled
// to scratch: WRITE 23->49MB). R14 structure; phase1 direct loop (no v[20]);
// phase2 mt-outer/s-inner inline loads; launch_bounds(512,2) so the register
// budget is not artificially shrunk (second arg = min waves/EU!).
// ---------------------------------------------------------------------------

#define NB 256
#define NR 6890
#define NJ 24
#define RD3 (NR*3)  // 20670
#define KPD 207
#define K2C 8       // k2 r-chunks
#define K2R 862     // rows per chunk
#define NT4 431     // vertex-tiles of 16 (431*16 = 6896 >= 6890)
#define BROW 232    // bsm row stride in bf16 (464B)
#define VROWB 264   // vps row stride in bf16 (528B)

// ---- output offsets (floats) ----
#define OFF_BETAS 0
#define OFF_POSE  2560
#define OFF_RSH   20992
#define OFF_RA    21760
#define OFF_VERTS 23296
#define OFF_VRED  5314816
#define OFF_NEWJ  5322496
#define OFF_VOFF  5340928

// ---- workspace offsets (floats) ----
#define WS_RS    0         // Rs: 256*24*9 = 55296
#define WS_PF    55296     // pose_feat: 256*207 = 52992 -> ends 108288
#define WS_BETA  108288    // 2560
#define WS_RSH   110848    // 768
#define WS_GI    111616    // 256 ints
#define WS_ORD   111872    // 256 ints
#define WS_CNT   112128    // 2 ints (+2 pad)
#define WS_PFB   112904    // bf16 A-matrix: 2*256*224 ushort = 57344 floats
#define WS_AT    170248    // packed At per batch: hi[12][32]+lo[12][32] ushort

typedef short v8s __attribute__((ext_vector_type(8)));
typedef float v4f __attribute__((ext_vector_type(4)));

__constant__ int PAR_c[24] = {0,0,0,0,1,2,3,4,5,6,7,8,9,9,9,12,13,14,16,17,18,19,20,21};
__constant__ int VL_c[10]  = {1325,336,1032,4515,1374,4848,1739,5209,1960,5423};
__constant__ int SY_c[10]  = {3,15,4,5,7,8,18,19,20,21};
__constant__ int LVL_j[23]  = {1,2,3, 4,5,6, 7,8,9, 10,11,12,13,14, 15,16,17, 18,19, 20,21, 22,23};
__constant__ int LVL_off[9] = {0,3,6,9,14,17,19,21,23};

__constant__ float BLO[72] = {
  -0.5933865286111969f, -6.283185307179586f, -1.215762200416361f,
  -1.5793940868065197f, -0.5881754611f, -0.5323249722f,
  -1.5793940868065197f, -0.5689768556f, -0.6736965222f,
  -1.0471975511965976f, -0.08726646259971647f, -0.08726646259971647f,
  -0.02268926111f, -0.01f, -0.01f,
  -0.02268926111f, -0.01f, -0.01f,
  -1.0471975511965976f, -0.08726646259971647f, -0.08726646259971647f,
  -0.5235987755982988f, -0.5235987755982988f, -0.5235987755982988f,
  -0.5235987755982988f, -0.5235987755982988f, -0.5235987755982988f,
  -1.0471975511965976f, -0.08726646259971647f, -0.08726646259971647f,
  -0.01f, -0.01f, -0.01f, -0.01f, -0.01f, -0.01f,
  -1.0471975511965976f, -0.08726646259971647f, -0.08726646259971647f,
  (float)(-1.551596394/3.0), (float)(-2.455676183/3.0), (float)(-1.570795/3.0),
  (float)(-1.551596394/3.0), (float)(-0.7627082389/3.0), (float)(-2.188641033/3.0),
  -1.0471975511965976f, -0.08726646259971647f, -0.08726646259971647f,
  (float)(-1.551596394*2.0/3.0), (float)(-2.455676183*2.0/3.0), (float)(-1.570795*2.0/3.0),
  (float)(-1.551596394*2.0/3.0), (float)(-0.7627082389*2.0/3.0), (float)(-2.188641033*2.0/3.0),
  -0.01f, -2.570867817f, -0.01f, -0.01f, -0.04799651389f, -0.01f,
  -0.5235987755982988f, -0.5235987755982988f, -0.5235987755982988f,
  -0.5235987755982988f, -0.5235987755982988f, -0.5235987755982988f,
  -0.01f, -0.01f, -0.01f, -0.01f, -0.01f, -0.01f
};
__constant__ float BHI[72] = {
  0.5933865286111969f, 6.283185307179586f, 1.215762200416361f,
  0.3097956806f, 0.5689768556f, 0.6736965222f,
  0.3097956806f, 0.5881754611f, 0.5323249722f,
  1.0471975511965976f, 0.08726646259971647f, 0.08726646259971647f,
  2.441713561f, 0.01f, 0.01f,
  2.441713561f, 0.01f, 0.01f,
  1.0471975511965976f, 0.08726646259971647f, 0.08726646259971647f,
  0.5235987755982988f, 0.5235987755982988f, 0.5235987755982988f,
  0.5235987755982988f, 0.5235987755982988f, 0.5235987755982988f,
  1.0471975511965976f, 0.08726646259971647f, 0.08726646259971647f,
  0.01f, 0.01f, 0.01f, 0.01f, 0.01f, 0.01f,
  1.0471975511965976f, 0.08726646259971647f, 0.08726646259971647f,
  (float)(2.206094311/3.0), (float)(0.7627082389/3.0), (float)(2.188641033/3.0),
  (float)(2.206094311/3.0), (float)(2.455676183/3.0), (float)(1.570795/3.0),
  1.0471975511965976f, 0.08726646259971647f, 0.08726646259971647f,
  (float)(2.206094311*2.0/3.0), (float)(0.7627082389*2.0/3.0), (float)(2.188641033*2.0/3.0),
  (float)(2.206094311*2.0/3.0), (float)(2.455676183*2.0/3.0), (float)(1.570795*2.0/3.0),
  0.01f, 0.04799651389f, 0.01f, 0.01f, 2.570867817f, 0.01f,
  0.5235987755982988f, 0.5235987755982988f, 0.5235987755982988f,
  0.5235987755982988f, 0.5235987755982988f, 0.5235987755982988f,
  0.01f, 0.01f, 0.01f, 0.01f, 0.01f, 0.01f
};

__device__ __forceinline__ unsigned short f2bf(float f) {
  union { float f; unsigned u; } c; c.f = f;
  const unsigned u = c.u + 0x7FFFu + ((c.u >> 16) & 1u);   // RNE
  return (unsigned short)(u >> 16);
}
__device__ __forceinline__ float bf2f(unsigned short h) {
  union { unsigned u; float f; } c; c.u = (unsigned)h << 16; return c.f;
}

// ---------------------------------------------------------------------------
// kA: block-partitioned merge of k1 (per-batch pose, 256 blocks) and
// k2 (joint-regressor partials, 384 blocks). 256 threads.
// ---------------------------------------------------------------------------
__global__ void kA_front(const float* __restrict__ x, const float* __restrict__ gen,
                         const float* __restrict__ vtemp, const float* __restrict__ sdirs,
                         const float* __restrict__ jreg,
                         float* __restrict__ out, float* __restrict__ W)
{
  const int bid = blockIdx.x;
  const int tid = threadIdx.x;

  if (bid < NB) {
    const int b = bid;
    const float* xb = x + b * 88;
    if (tid < 24) {
      const int j = tid;
      float t[3];
      if (j == 0) {
        t[0] = atan2f(xb[16], xb[13]);
        t[1] = atan2f(xb[17], xb[14]);
        t[2] = atan2f(xb[18], xb[15]);
      } else {
        t[0] = xb[19 + (j - 1) * 3 + 0];
        t[1] = xb[19 + (j - 1) * 3 + 1];
        t[2] = xb[19 + (j - 1) * 3 + 2];
      }
#pragma unroll
      for (int c = 0; c < 3; c++) {
        const int pi = j * 3 + c;
        const float lo = 2.f * BLO[pi], hi = 2.f * BHI[pi];
        const float mean = 0.5f * (lo + hi);
        const float scale = 2.f / fabsf(lo - hi);
        const float v = tanhf((t[c] - mean) * scale) / scale + mean;
        t[c] = v;
        out[OFF_POSE + b * 72 + pi] = v;
      }
      const float a0 = t[0] + 1e-8f, a1 = t[1] + 1e-8f, a2 = t[2] + 1e-8f;
      const float ang = sqrtf(a0 * a0 + a1 * a1 + a2 * a2);
      const float half = 0.5f * ang;
      const float sh = sinf(half), ch = cosf(half);
      const float inv = sh / ang;
      float qw = ch, qx = t[0] * inv, qy = t[1] * inv, qz = t[2] * inv;
      const float nn = sqrtf(qw * qw + qx * qx + qy * qy + qz * qz);
      qw /= nn; qx /= nn; qy /= nn; qz /= nn;
      float R[9];
      R[0] = 1.f - 2.f * (qy * qy + qz * qz); R[1] = 2.f * (qx * qy - qw * qz); R[2] = 2.f * (qx * qz + qw * qy);
      R[3] = 2.f * (qx * qy + qw * qz); R[4] = 1.f - 2.f * (qx * qx + qz * qz); R[5] = 2.f * (qy * qz - qw * qx);
      R[6] = 2.f * (qx * qz - qw * qy); R[7] = 2.f * (qy * qz + qw * qx); R[8] = 1.f - 2.f * (qx * qx + qy * qy);
      float* rsw = W + WS_RS + (size_t)(b * 24 + j) * 9;
#pragma unroll
      for (int e = 0; e < 9; e++) rsw[e] = R[e];
      if (j >= 1) {
        float* pfw = W + WS_PF + (size_t)b * 207 + (j - 1) * 9;
#pragma unroll
        for (int e = 0; e < 9; e++)
          pfw[e] = R[e] - ((e == 0 || e == 4 || e == 8) ? 1.f : 0.f);
      }
    } else if (tid < 34) {
      const int k = tid - 24;
      const float v = tanhf(xb[k] / 3.0f) * 3.0f;
      out[OFF_BETAS + b * 10 + k] = v;
      W[WS_BETA + b * 10 + k] = v;
    } else if (tid == 34) {
      const float r0 = xb[10] + (0.6f - 0.286f);
      const float r1 = xb[11] + (1.2f - 0.286f);
      const float r2 = xb[12] + 0.1f;
      out[OFF_RSH + b * 3 + 0] = r0; out[OFF_RSH + b * 3 + 1] = r1; out[OFF_RSH + b * 3 + 2] = r2;
      W[WS_RSH + b * 3 + 0] = r0; W[WS_RSH + b * 3 + 1] = r1; W[WS_RSH + b * 3 + 2] = r2;
#pragma unroll
      for (int k2 = 0; k2 < 6; k2++) out[OFF_RA + b * 6 + k2] = xb[13 + k2];
    } else if (tid == 35) {
      ((int*)(W + WS_GI))[b] = (gen[b * 2 + 1] > gen[b * 2 + 0]) ? 1 : 0;
    }
    return;
  }

  // ---------------- k2 part ----------------
  const int kb = bid - NB;
  const int c = kb % K2C, j = (kb / K2C) % 24, g = kb / (K2C * 24);
  const int r0 = c * K2R;
  int r1 = r0 + K2R; if (r1 > NR) r1 = NR;
  const float* vtg = vtemp + (size_t)g * NR * 3;
  const float* sdg = sdirs + (size_t)g * 10 * NR * 3;
  const float* jrg = jreg + (size_t)g * NR * 24;
  float acc[33];
#pragma unroll
  for (int e = 0; e < 33; e++) acc[e] = 0.f;
  for (int r = r0 + tid; r < r1; r += 256) {
    const float w = jrg[r * 24 + j];
    acc[0] += vtg[r * 3 + 0] * w;
    acc[1] += vtg[r * 3 + 1] * w;
    acc[2] += vtg[r * 3 + 2] * w;
#pragma unroll
    for (int k = 0; k < 10; k++) {
      const float* s = sdg + ((size_t)k * NR + r) * 3;
      acc[3 + k * 3 + 0] += s[0] * w;
      acc[3 + k * 3 + 1] += s[1] * w;
      acc[3 + k * 3 + 2] += s[2] * w;
    }
  }
  __shared__ float red[4][33];
  const int lane = tid & 63, wv = tid >> 6;
#pragma unroll
  for (int e = 0; e < 33; e++) {
    float v = acc[e];
    v += __shfl_down(v, 32); v += __shfl_down(v, 16); v += __shfl_down(v, 8);
    v += __shfl_down(v, 4);  v += __shfl_down(v, 2);  v += __shfl_down(v, 1);
    if (lane == 0) red[wv][e] = v;
  }
  __syncthreads();
  if (tid < 33) {
    const int e = tid;
    out[OFF_VERTS + (size_t)(((g * 24 + j) * K2C + c) * 33 + e)] =
        red[0][e] + red[1][e] + red[2][e] + red[3][e];
  }
}

// ---------------------------------------------------------------------------
// kB: merge of (in-block gender compaction + PFB pack, 512 blocks) and
// k3 kinematic chain (256 blocks). 256 threads.
// ---------------------------------------------------------------------------
__global__ void kB_mid(float* __restrict__ out, float* __restrict__ W)
{
  const int bid = blockIdx.x;
  const int tid = threadIdx.x;

  if (bid < 512) {
    __shared__ int s_ord[NB];
    __shared__ int s_c0[4];
    const int gib = ((const int*)(W + WS_GI))[tid];
    const int lane = tid & 63, wvi = tid >> 6;
    const unsigned long long b0 = __ballot(gib == 0);
    if (lane == 0) s_c0[wvi] = __popcll(b0);
    __syncthreads();
    const int t0 = s_c0[0] + s_c0[1] + s_c0[2] + s_c0[3];
    int off0 = 0, off1 = t0;
    for (int w = 0; w < wvi; w++) { off0 += s_c0[w]; off1 += 64 - s_c0[w]; }
    const unsigned long long ltm = (1ull << lane) - 1ull;
    const int rr0 = __popcll(b0 & ltm);
    const int rr1 = lane - rr0;
    if (gib == 0) s_ord[off0 + rr0] = tid;
    else          s_ord[off1 + rr1] = tid;
    __syncthreads();

    if (bid == 0) {
      ((int*)(W + WS_ORD))[tid] = s_ord[tid];
      if (tid == 0) { ((int*)(W + WS_CNT))[0] = t0; ((int*)(W + WS_CNT))[1] = NB - t0; }
    }

    const int g = bid >> 8, m = bid & 255;
    const int n_g = g ? (NB - t0) : t0;
    const int g0off = g ? t0 : 0;
    if (tid < 224) {
      float v = 0.f;
      if (m < n_g) {
        const int b = s_ord[g0off + m];
        if (tid < KPD)        v = W[WS_PF + (size_t)b * KPD + tid];
        else if (tid < 217)   v = W[WS_BETA + b * 10 + (tid - KPD)];
        else if (tid == 217)  v = 1.f;
      }
      ((unsigned short*)(W + WS_PFB))[((size_t)g * 256 + m) * 224 + tid] = f2bf(v);
    }
    return;
  }

  // -------- k3 part: b = bid - 512 --------
  const int b = bid - 512;
  __shared__ float J[72];
  __shared__ float G[24][12];
  __shared__ float sA[24][12];
  __shared__ float j0s[3];
  const int gi = ((const int*)(W + WS_GI))[b];
  float bb[10];
#pragma unroll
  for (int k = 0; k < 10; k++) bb[k] = W[WS_BETA + b * 10 + k];

  if (tid < 72) {
    const int j = tid / 3, d = tid % 3;
    float v = 0.f;
#pragma unroll
    for (int c = 0; c < K2C; c++) {
      const float* P = out + OFF_VERTS + (size_t)(((gi * 24 + j) * K2C + c) * 33);
      float s = P[d];
#pragma unroll
      for (int k = 0; k < 10; k++) s += bb[k] * P[3 + k * 3 + d];
      v += s;
    }
    J[tid] = v;
  }
  __syncthreads();
  const float* Rs = W + WS_RS + (size_t)b * 216;
  if (tid < 12) {
    const int row = tid / 4, col = tid % 4;
    G[0][tid] = (col < 3) ? Rs[row * 3 + col] : J[row];
  }
  __syncthreads();
#pragma unroll
  for (int L = 0; L < 8; L++) {
    const int base = LVL_off[L];
    const int cntL = LVL_off[L + 1] - base;
    const int slot = tid / 12, e = tid - slot * 12;
    if (slot < cntL) {
      const int i = LVL_j[base + slot];
      const int p = PAR_c[i];
      const int row = e / 4, col = e - row * 4;
      const float* Ri = Rs + i * 9;
      const float g0 = G[p][row * 4 + 0], g1 = G[p][row * 4 + 1], g2 = G[p][row * 4 + 2];
      float v;
      if (col < 3) {
        v = g0 * Ri[col] + g1 * Ri[3 + col] + g2 * Ri[6 + col];
      } else {
        const float t0 = J[i * 3 + 0] - J[p * 3 + 0];
        const float t1 = J[i * 3 + 1] - J[p * 3 + 1];
        const float t2 = J[i * 3 + 2] - J[p * 3 + 2];
        v = g0 * t0 + g1 * t1 + g2 * t2 + G[p][row * 4 + 3];
      }
      G[i][e] = v;
    }
    __syncthreads();
  }
  if (tid < 3)
    j0s[tid] = W[WS_RSH + b * 3 + tid] - J[tid];
  __syncthreads();
  if (tid < 72) {
    const int j = tid / 3, d = tid % 3;
    out[OFF_NEWJ + (size_t)b * 72 + tid] = G[j][d * 4 + 3] + j0s[d];
  }
  for (int e = tid; e < 288; e += 256) {
    const int j = e / 12, rc = e - j * 12, row = rc / 4, col = rc - row * 4;
    float v = G[j][rc];
    if (col == 3)
      v -= G[j][row * 4 + 0] * J[j * 3 + 0] + G[j][row * 4 + 1] * J[j * 3 + 1] + G[j][row * 4 + 2] * J[j * 3 + 2];
    sA[j][rc] = v;
  }
  __syncthreads();
  unsigned short* at = (unsigned short*)(W + WS_AT) + (size_t)b * 768;
  for (int e = tid; e < 384; e += 256) {
    const int c = e >> 5, j = e & 31;
    float a = 0.f;
    if (j < 24) a = sA[j][c];
    else if (j == 24) a = ((c & 3) == 3) ? j0s[c >> 2] : 0.f;
    const unsigned short h = f2bf(a);
    const unsigned short l = f2bf(a - bf2f(h));
    at[c * 32 + j] = h;
    at[384 + c * 32 + j] = l;
  }
}

// ---------------------------------------------------------------------------
// K4 fused (512 threads / 8 waves): pose-GEMM + skinning, v_posed in LDS(bf16).
// Grid: x = vertex tile (16 verts = 48 n-rows), y = gender.
// Minimal live state everywhere (no hoisted prefetch: spills cost more).
// ---------------------------------------------------------------------------
__launch_bounds__(512, 2)
__global__ void k4_fused(const float* __restrict__ pd, const float* __restrict__ vtemp,
                         const float* __restrict__ sdirs, const float* __restrict__ wts,
                         float* __restrict__ out, const float* __restrict__ W)
{
  __shared__ __align__(16) unsigned short bsm[48][BROW];
  __shared__ __align__(16) unsigned short vps[48][VROWB];
  __shared__ int s_ord[NB];

  const int tid = threadIdx.x;
  const int wave = tid >> 6, lane = tid & 63;
  const int g = blockIdx.y;
  const int nfrac = lane & 15;
  const int kq = (lane >> 4) * 8;
  const int tile = blockIdx.x;
  const int n0 = tile * 48;
  const int rbase = tile * 16;

  const int* cnt = (const int*)(W + WS_CNT);
  const int* ord = (const int*)(W + WS_ORD);
  const int nh = cnt[g];
  const int g0off = g ? cnt[0] : 0;
  if (nh <= 0) return;   // uniform, before any barrier

  if (tid < NB) s_ord[tid] = ord[tid];

  // ---- Phase 1: stage B tile (direct unrolled load->convert->LDS) ----
  const int nrows = (RD3 - n0 < 48) ? (RD3 - n0) : 48;
  const int nflat = nrows * KPD;                     // <= 9936
  const float* src = pd + ((size_t)g * RD3 + n0) * KPD;
#pragma unroll
  for (int i = 0; i < 5; i++) {
    const int e4 = (i * 512 + tid) * 4;
    if (e4 + 3 < nflat) {
      float t4[4];
      __builtin_memcpy(t4, src + e4, 16);
#pragma unroll
      for (int t = 0; t < 4; t++) {
        const int fl = e4 + t;
        bsm[fl / KPD][fl % KPD] = f2bf(t4[t]);
      }
    } else if (e4 < nflat) {
      for (int t = 0; t < 4 && e4 + t < nflat; t++)
        bsm[(e4 + t) / KPD][(e4 + t) % KPD] = f2bf(src[e4 + t]);
    }
  }
  if (tid < 480) {
    const int r_ = tid / 10, kk = tid - r_ * 10;
    const int nr = (n0 + r_ < RD3) ? (n0 + r_) : (RD3 - 1);
    const int rr = nr / 3, dd = nr - rr * 3;
    bsm[r_][KPD + kk] = f2bf(sdirs[((size_t)(g * 10 + kk) * NR + rr) * 3 + dd]);
  }
  if (tid >= 464) {
    const int r_ = tid - 464;
    const int nr = (n0 + r_ < RD3) ? (n0 + r_) : (RD3 - 1);
    const int rr = nr / 3, dd = nr - rr * 3;
    bsm[r_][217] = f2bf(vtemp[((size_t)g * NR + rr) * 3 + dd]);
  }
  if (tid < 288) {
    const int r_ = tid / 6, kk = 218 + (tid - r_ * 6);
    bsm[r_][kk] = 0;
  }
  __syncthreads();

  // ---- Phase 2: GEMM -> vps (bf16). mt outer (A once), s inner ----
  const unsigned short* pfb = (const unsigned short*)(W + WS_PFB) + (size_t)g * 256 * 224;
  const int mtmax = (nh + 15) >> 4;
  for (int mt = wave; mt < mtmax; mt += 8) {
    const unsigned short* ap = pfb + (size_t)(mt * 16 + nfrac) * 224 + kq;
    v8s af[7];
#pragma unroll
    for (int c = 0; c < 7; c++) af[c] = *(const v8s*)(ap + c * 32);
#pragma unroll
    for (int s = 0; s < 3; s++) {
      const unsigned short* bp = &bsm[s * 16 + nfrac][0];
      v8s bfr[7];
#pragma unroll
      for (int c = 0; c < 7; c++) bfr[c] = *(const v8s*)(bp + c * 32 + kq);

      v4f acc0 = {0.f, 0.f, 0.f, 0.f};
      v4f acc1 = {0.f, 0.f, 0.f, 0.f};
      acc0 = __builtin_amdgcn_mfma_f32_16x16x32_bf16(af[0], bfr[0], acc0, 0, 0, 0);
      acc1 = __builtin_amdgcn_mfma_f32_16x16x32_bf16(af[1], bfr[1], acc1, 0, 0, 0);
      acc0 = __builtin_amdgcn_mfma_f32_16x16x32_bf16(af[2], bfr[2], acc0, 0, 0, 0);
      acc1 = __builtin_amdgcn_mfma_f32_16x16x32_bf16(af[3], bfr[3], acc1, 0, 0, 0);
      acc0 = __builtin_amdgcn_mfma_f32_16x16x32_bf16(af[4], bfr[4], acc0, 0, 0, 0);
      acc1 = __builtin_amdgcn_mfma_f32_16x16x32_bf16(af[5], bfr[5], acc1, 0, 0, 0);
      acc0 = __builtin_amdgcn_mfma_f32_16x16x32_bf16(af[6], bfr[6], acc0, 0, 0, 0);

      const int ln = s * 16 + nfrac;
      const int lm0 = mt * 16 + (lane >> 4) * 4;
#pragma unroll
      for (int j = 0; j < 4; j++)
        vps[ln][lm0 + j] = f2bf(acc0[j] + acc1[j]);
    }
  }
  __syncthreads();

  // ---- Phase 3: skinning, two batches per iteration ----
  const int f = nfrac, q = lane >> 4;
  const int r = rbase + f;
  const int rc = (r < NR) ? r : (NR - 1);

  int vli = -1;
#pragma unroll
  for (int i = 0; i < 10; i++) if (r == VL_c[i]) vli = i;
  const int syj = (vli >= 0) ? SY_c[vli] : 0;

  v8s wh, wl;
  {
    union { v8s v; unsigned short s[8]; } H, L;
    if (q < 3) {
      float fw[8];
      __builtin_memcpy(fw, wts + ((size_t)g * NR + rc) * 24 + q * 8, 32);
#pragma unroll
      for (int t = 0; t < 8; t++) { H.s[t] = f2bf(fw[t]); L.s[t] = f2bf(fw[t] - bf2f(H.s[t])); }
    } else {
#pragma unroll
      for (int t = 0; t < 8; t++) { H.s[t] = (t == 0) ? 0x3F80 : 0; L.s[t] = 0; }
    }
    wh = H.v; wl = L.v;
  }

  const unsigned short* at = (const unsigned short*)(W + WS_AT);
  const int fragoff = f * 32 + q * 8;

  for (int lm = wave; lm < nh; lm += 16) {
    const int lmB = lm + 8;
    const bool hasB = (lmB < nh);
    const int lmBc = hasB ? lmB : lm;
    const int b1 = s_ord[g0off + lm];
    const int b2 = s_ord[g0off + lmBc];
    const v8s ah1 = *(const v8s*)(at + (size_t)b1 * 768 + fragoff);
    const v8s al1 = *(const v8s*)(at + (size_t)b1 * 768 + 384 + fragoff);
    const v8s ah2 = *(const v8s*)(at + (size_t)b2 * 768 + fragoff);
    const v8s al2 = *(const v8s*)(at + (size_t)b2 * 768 + 384 + fragoff);
    const float vx1 = bf2f(vps[f * 3 + 0][lm]);
    const float vy1 = bf2f(vps[f * 3 + 1][lm]);
    const float vz1 = bf2f(vps[f * 3 + 2][lm]);
    const float vx2 = bf2f(vps[f * 3 + 0][lmBc]);
    const float vy2 = bf2f(vps[f * 3 + 1][lmBc]);
    const float vz2 = bf2f(vps[f * 3 + 2][lmBc]);

    v4f accA = {0.f, 0.f, 0.f, 0.f};
    v4f accB = {0.f, 0.f, 0.f, 0.f};
    accA = __builtin_amdgcn_mfma_f32_16x16x32_bf16(ah1, wh, accA, 0, 0, 0);
    accB = __builtin_amdgcn_mfma_f32_16x16x32_bf16(ah2, wh, accB, 0, 0, 0);
    accA = __builtin_amdgcn_mfma_f32_16x16x32_bf16(ah1, wl, accA, 0, 0, 0);
    accB = __builtin_amdgcn_mfma_f32_16x16x32_bf16(ah2, wl, accB, 0, 0, 0);
    accA = __builtin_amdgcn_mfma_f32_16x16x32_bf16(al1, wh, accA, 0, 0, 0);
    accB = __builtin_amdgcn_mfma_f32_16x16x32_bf16(al2, wh, accB, 0, 0, 0);

    const float o1 = accA[0] * vx1 + accA[1] * vy1 + accA[2] * vz1 + accA[3];
    const float o2 = accB[0] * vx2 + accB[1] * vy2 + accB[2] * vz2 + accB[3];
    if (q < 3 && r < NR) {
      out[OFF_VERTS + ((size_t)b1 * NR + r) * 3 + q] = o1;
      if (hasB) out[OFF_VERTS + ((size_t)b2 * NR + r) * 3 + q] = o2;
      if (vli >= 0) {
        out[OFF_VRED + ((size_t)b1 * 10 + vli) * 3 + q] = o1;
        out[OFF_VOFF + ((size_t)b1 * 10 + vli) * 3 + q] =
            o1 - out[OFF_NEWJ + (size_t)b1 * 72 + syj * 3 + q];
        if (hasB) {
          out[OFF_VRED + ((size_t)b2 * 10 + vli) * 3 + q] = o2;
          out[OFF_VOFF + ((size_t)b2 * 10 + vli) * 3 + q] =
              o2 - out[OFF_NEWJ + (size_t)b2 * 72 + syj * 3 + q];
        }
      }
    }
  }
}

// ---------------------------------------------------------------------------
extern "C" void kernel_launch(void* const* d_in, const int* in_sizes, int n_in,
                              void* d_out, int out_size, void* d_ws, size_t ws_size,
                              hipStream_t stream)
{
  const float* x   = (const float*)d_in[0];
  const float* gen = (const float*)d_in[1];
  const float* vt  = (const float*)d_in[2];
  const float* sd  = (const float*)d_in[3];
  const float* jr  = (const float*)d_in[4];
  const float* pd  = (const float*)d_in[5];
  const float* wt  = (const float*)d_in[6];
  float* out = (float*)d_out;
  float* W   = (float*)d_ws;

  kA_front<<<NB + 2 * 24 * K2C, 256, 0, stream>>>(x, gen, vt, sd, jr, out, W);
  kB_mid<<<512 + NB, 256, 0, stream>>>(out, W);
  k4_fused<<<dim3(NT4, 2), 512, 0, stream>>>(pd, vt, sd, wt, out, W);
}